// Round 10
// baseline (470.196 us; speedup 1.0000x reference)
//
#include <hip/hip_runtime.h>
#include <hip/hip_bf16.h>
#include <stdint.h>

typedef unsigned short u16;
typedef _Float16 f16;
typedef __attribute__((ext_vector_type(4))) float f32x4;
typedef __attribute__((ext_vector_type(8))) _Float16 h16x8;
typedef __attribute__((ext_vector_type(4))) _Float16 h16x4;

#define LN_EPS 1e-5f
#define ATT_EPS 1e-8f

// ---------------- init slots: mu + exp(logsigma)*noise ----------------
__global__ __launch_bounds__(256) void init_slots_k(
    const float* __restrict__ noise, const float* __restrict__ mu,
    const float* __restrict__ lsig, float* __restrict__ slots)
{
  int i = blockIdx.x * 256 + threadIdx.x;   // 65536 total
  int d = i & 255;
  slots[i] = mu[d] + __expf(lsig[d]) * noise[i];
}

// ---------------- prep weights: WkT f16, wihT/whhT f32 ----------------
__global__ __launch_bounds__(256) void prep_w_k(
    const float* __restrict__ Wk, const float* __restrict__ wih,
    const float* __restrict__ whh,
    f16* __restrict__ WkT16, float* __restrict__ wihT, float* __restrict__ whhT)
{
  int i = blockIdx.x * 256 + threadIdx.x;   // grid 768 -> 196608
  if (i < 65536) {                           // WkT[c][kd] = Wk[kd][c]
    int c = i >> 8, kd = i & 255;
    WkT16[i] = (f16)Wk[kd * 256 + c];
  }
  int d = i / 768, j = i - d * 768;
  wihT[i] = wih[j * 256 + d];
  whhT[i] = whh[j * 256 + d];
}

// ---------------- pure LN pass: xln16 = LN(inputs) as f16 ----------------
// grid 2048, block 256 (4 waves): one wave per row, 16 rows/wave
__global__ __launch_bounds__(256) void ln_x_k(
    const float* __restrict__ inputs, const float* __restrict__ g_in,
    const float* __restrict__ b_in, f16* __restrict__ xln16)
{
  int t = threadIdx.x, w = t >> 6, l = t & 63;
  float4 gv = *(const float4*)(g_in + l * 4);
  float4 bv = *(const float4*)(b_in + l * 4);
  long row0 = (long)blockIdx.x * 64 + w * 16;
#pragma unroll 2
  for (int i = 0; i < 16; i++) {
    long r = row0 + i;
    float4 x = *(const float4*)(inputs + r * 256 + l * 4);
    float s1 = x.x + x.y + x.z + x.w;
    float s2 = x.x * x.x + x.y * x.y + x.z * x.z + x.w * x.w;
#pragma unroll
    for (int off = 1; off < 64; off <<= 1) {
      s1 += __shfl_xor(s1, off);
      s2 += __shfl_xor(s2, off);
    }
    float m = s1 * (1.f / 256.f);
    float var = s2 * (1.f / 256.f) - m * m;
    float rs = rsqrtf(var + LN_EPS);
    h16x4 o;
    o[0] = (f16)((x.x - m) * rs * gv.x + bv.x);
    o[1] = (f16)((x.y - m) * rs * gv.y + bv.y);
    o[2] = (f16)((x.z - m) * rs * gv.z + bv.z);
    o[3] = (f16)((x.w - m) * rs * gv.w + bv.w);
    *(h16x4*)(xln16 + r * 256 + l * 4) = o;
  }
}

// ---------------- t = (LN(slots)@Wq) projected through Wk heads, x SCALE ----
// grid 256 (one slot row per block), block 1024 (iter-0 only)
__global__ __launch_bounds__(1024) void slot_t_k(
    const float* __restrict__ slots, const float* __restrict__ g_sl,
    const float* __restrict__ b_sl, const float* __restrict__ Wq,
    const f16* __restrict__ WkT16, f16* __restrict__ tq)
{
  __shared__ float ln[256];
  __shared__ float qs[256];
  __shared__ float part[4][256];
  __shared__ float red[8];
  int t = threadIdx.x;
  int i = blockIdx.x;
  if (t < 256) {
    float x = slots[i * 256 + t];
    float a = x, bq = x * x;
#pragma unroll
    for (int off = 32; off; off >>= 1) { a += __shfl_down(a, off); bq += __shfl_down(bq, off); }
    if ((t & 63) == 0) { red[t >> 6] = a; red[4 + (t >> 6)] = bq; }
  }
  __syncthreads();
  if (t < 256) {
    float x = slots[i * 256 + t];
    float S1 = red[0] + red[1] + red[2] + red[3];
    float S2 = red[4] + red[5] + red[6] + red[7];
    float m = S1 * (1.f / 256.f);
    float var = S2 * (1.f / 256.f) - m * m;
    float rstd = rsqrtf(var + LN_EPS);
    ln[t] = (x - m) * rstd * g_sl[t] + b_sl[t];
  }
  __syncthreads();
  int col = t & 255, ks = t >> 8;
  float acc = 0.f;
#pragma unroll 16
  for (int dd = 0; dd < 64; dd++) {
    int d = ks * 64 + dd;
    acc += ln[d] * Wq[d * 256 + col];
  }
  part[ks][col] = acc;
  __syncthreads();
  if (t < 256) qs[t] = part[0][t] + part[1][t] + part[2][t] + part[3][t];
  __syncthreads();
  int h = t >> 8, d2 = t & 255;
  float tt = 0.f;
#pragma unroll 8
  for (int dp = 0; dp < 64; dp++)
    tt += qs[h * 64 + dp] * (float)WkT16[(h * 64 + dp) * 256 + d2];
  tq[((i >> 3) * 32 + h * 8 + (i & 7)) * 256 + d2] = (f16)(tt * 0.125f);
}

// ---------------- fused attn: MFMA dots + shuffle softmax + MFMA PV ----------
// grid (32 b, 32 nchunk of 128 n), block 256 (4 waves). 2 subtiles of 64 n.
__global__ __launch_bounds__(256, 3) void attn_fused_k(
    const f16* __restrict__ xln16, const f16* __restrict__ tq,
    f16* __restrict__ y_part, float* __restrict__ sums_part)
{
  __shared__ u16 xsT[256 * 64];      // 32KB: addr = d*128 + ((n8 ^ (d&7))<<4)
  __shared__ u16 attT[32 * 64];      // 4KB:  addr = hs*128 + ((n8 ^ (hs&7))<<4)
  __shared__ float asum_s[4][32];
  int b = blockIdx.x, nc = blockIdx.y, t = threadIdx.x;
  int nb = nc * 128;
  int w = t >> 6, l = t & 63;
  int lc = l & 15, lg = l >> 4;
  h16x8 tb0[8], tb1[8];
#pragma unroll
  for (int k0 = 0; k0 < 8; k0++) {
    tb0[k0] = *(const h16x8*)(tq + (b * 32 + lc) * 256 + k0 * 32 + lg * 8);
    tb1[k0] = *(const h16x8*)(tq + (b * 32 + lc + 16) * 256 + k0 * 32 + lg * 8);
  }
  f32x4 acc0[4], acc1[4];
#pragma unroll
  for (int dt = 0; dt < 4; dt++) { acc0[dt] = (f32x4){0,0,0,0}; acc1[dt] = (f32x4){0,0,0,0}; }
  float as0 = 0.f, as1 = 0.f;

  for (int sub = 0; sub < 2; sub++) {
    __syncthreads();
    {
      int nl8 = t >> 5, dchunk = t & 31;
      const f16* gp = xln16 + ((long)(b * 4096 + nb + sub * 64 + nl8 * 8)) * 256 + dchunk * 8;
      h16x8 v0 = *(const h16x8*)(gp);
      h16x8 v1 = *(const h16x8*)(gp + 256);
      h16x8 v2 = *(const h16x8*)(gp + 512);
      h16x8 v3 = *(const h16x8*)(gp + 768);
      h16x8 v4 = *(const h16x8*)(gp + 1024);
      h16x8 v5 = *(const h16x8*)(gp + 1280);
      h16x8 v6 = *(const h16x8*)(gp + 1536);
      h16x8 v7 = *(const h16x8*)(gp + 1792);
#pragma unroll
      for (int j = 0; j < 8; j++) {
        h16x8 o;
        o[0] = v0[j]; o[1] = v1[j]; o[2] = v2[j]; o[3] = v3[j];
        o[4] = v4[j]; o[5] = v5[j]; o[6] = v6[j]; o[7] = v7[j];
        int d = dchunk * 8 + j;
        *(h16x8*)((char*)xsT + d * 128 + ((nl8 ^ j) << 4)) = o;
      }
    }
    f32x4 D0 = {0,0,0,0}, D1 = {0,0,0,0};
    {
      const f16* ga = xln16 + ((long)(b * 4096 + nb + sub * 64 + w * 16 + lc)) * 256 + lg * 8;
#pragma unroll
      for (int k0 = 0; k0 < 8; k0++) {
        h16x8 af = *(const h16x8*)(ga + k0 * 32);
        D0 = __builtin_amdgcn_mfma_f32_16x16x32_f16(af, tb0[k0], D0, 0, 0, 0);
        D1 = __builtin_amdgcn_mfma_f32_16x16x32_f16(af, tb1[k0], D1, 0, 0, 0);
      }
    }
    h16x4 pk0, pk1;
#pragma unroll
    for (int r = 0; r < 4; r++) {
      float d0 = D0[r], d1 = D1[r];
      float m0 = d0, m1 = d1;
      m0 = fmaxf(m0, __shfl_xor(m0, 1)); m0 = fmaxf(m0, __shfl_xor(m0, 2)); m0 = fmaxf(m0, __shfl_xor(m0, 4));
      m1 = fmaxf(m1, __shfl_xor(m1, 1)); m1 = fmaxf(m1, __shfl_xor(m1, 2)); m1 = fmaxf(m1, __shfl_xor(m1, 4));
      float e0 = __expf(d0 - m0), e1 = __expf(d1 - m1);
      float s0 = e0, s1 = e1;
      s0 += __shfl_xor(s0, 1); s0 += __shfl_xor(s0, 2); s0 += __shfl_xor(s0, 4);
      s1 += __shfl_xor(s1, 1); s1 += __shfl_xor(s1, 2); s1 += __shfl_xor(s1, 4);
      f16 a0h = (f16)(e0 / s0), a1h = (f16)(e1 / s1);
      as0 += (float)a0h; as1 += (float)a1h;
      pk0[r] = a0h; pk1[r] = a1h;
    }
    {
      int slot = w * 2 + (lg >> 1);
      int boff = (lg & 1) * 8;
      *(h16x4*)((char*)attT + lc * 128 + ((slot ^ (lc & 7)) << 4) + boff) = pk0;
      *(h16x4*)((char*)attT + (lc + 16) * 128 + ((slot ^ (lc & 7)) << 4) + boff) = pk1;
    }
    __syncthreads();
    h16x8 A00, A01, A10, A11;
    {
      int hs0 = lc, hs1 = 16 + lc, sw = lc & 7;
      A00 = *(const h16x8*)((char*)attT + hs0 * 128 + ((lg ^ sw) << 4));
      A01 = *(const h16x8*)((char*)attT + hs0 * 128 + (((4 + lg) ^ sw) << 4));
      A10 = *(const h16x8*)((char*)attT + hs1 * 128 + ((lg ^ sw) << 4));
      A11 = *(const h16x8*)((char*)attT + hs1 * 128 + (((4 + lg) ^ sw) << 4));
    }
#pragma unroll
    for (int dt = 0; dt < 4; dt++) {
      int d = w * 64 + dt * 16 + lc;
      h16x8 B0 = *(const h16x8*)((char*)xsT + d * 128 + ((lg ^ (d & 7)) << 4));
      h16x8 B1 = *(const h16x8*)((char*)xsT + d * 128 + (((4 + lg) ^ (d & 7)) << 4));
      acc0[dt] = __builtin_amdgcn_mfma_f32_16x16x32_f16(A00, B0, acc0[dt], 0, 0, 0);
      acc0[dt] = __builtin_amdgcn_mfma_f32_16x16x32_f16(A01, B1, acc0[dt], 0, 0, 0);
      acc1[dt] = __builtin_amdgcn_mfma_f32_16x16x32_f16(A10, B0, acc1[dt], 0, 0, 0);
      acc1[dt] = __builtin_amdgcn_mfma_f32_16x16x32_f16(A11, B1, acc1[dt], 0, 0, 0);
    }
  }
  as0 += __shfl_xor(as0, 16); as0 += __shfl_xor(as0, 32);
  as1 += __shfl_xor(as1, 16); as1 += __shfl_xor(as1, 32);
  if (l < 16) { asum_s[w][l] = as0; asum_s[w][l + 16] = as1; }
  __syncthreads();
  if (t < 32)
    sums_part[(nc * 32 + b) * 32 + t] =
        asum_s[0][t] + asum_s[1][t] + asum_s[2][t] + asum_s[3][t];
  long ybase = ((long)(nc * 32 + b) * 32) * 256;
#pragma unroll
  for (int reg = 0; reg < 4; reg++) {
    int hsA = lg * 4 + reg;
#pragma unroll
    for (int dt = 0; dt < 4; dt++) {
      int d = w * 64 + dt * 16 + lc;
      y_part[ybase + hsA * 256 + d] = (f16)acc0[dt][reg];
      y_part[ybase + (16 + hsA) * 256 + d] = (f16)acc1[dt][reg];
    }
  }
}

// ---------------- combine: 2 slot-rows per block (weight reuse x2) ----------
// grid 128, block 1024. Stage structure identical to R9; every weight load
// feeds 2 rows' FMAs.
__global__ __launch_bounds__(1024) void combine_k(
    const f16* __restrict__ y_part, const float* __restrict__ sums_part,
    float* __restrict__ slots, const float* __restrict__ Wv,
    const float* __restrict__ Wc, const float* __restrict__ wihT,
    const float* __restrict__ whhT, const float* __restrict__ bih,
    const float* __restrict__ bhh, const float* __restrict__ g_ml,
    const float* __restrict__ b_ml, const float* __restrict__ W1,
    const float* __restrict__ b1, const float* __restrict__ W2,
    const float* __restrict__ b2, const float* __restrict__ g_sl,
    const float* __restrict__ b_sl, const float* __restrict__ Wq,
    const f16* __restrict__ WkT16, f16* __restrict__ tq, int cq)
{
  __shared__ float ysn[2][4][256];     // 8KB
  __shared__ float uls[2][256], cls[2][256], hls[2][256], sns[2][256], lns[2][256];
  __shared__ float hid[2][512];        // 4KB
  __shared__ float part2[4][256][2];   // 8KB
  __shared__ float part6[4][256][13];  // 53.2KB (12 used + pad)
  __shared__ float part5[2][512][2];   // 8KB
  __shared__ float red[16];
  int t = threadIdx.x;
  int i = blockIdx.x;                  // rows 2i, 2i+1
  int b = i >> 2, kp = (i & 3) * 2;
  // ---- y-reduce + normalize (both rows)
  {
    int j = t >> 8, d = t & 255;
#pragma unroll
    for (int rp = 0; rp < 2; rp++) {
      float den = ATT_EPS, yv = 0.f;
#pragma unroll 8
      for (int ncq = 0; ncq < 32; ncq++) {
        int hsrow = (ncq * 32 + b) * 32 + j * 8 + kp + rp;
        den += sums_part[hsrow];
        yv += (float)y_part[(long)hsrow * 256 + d];
      }
      ysn[rp][j][d] = yv / den;
    }
    if (t < 512) hls[t >> 8][t & 255] = slots[(2 * i + (t >> 8)) * 256 + (t & 255)];
  }
  __syncthreads();
  int col = t & 255, ks = t >> 8;
  // ---- Wv (block-diagonal per head)
  {
    int h = col >> 6;
    float a0 = 0.f, a1 = 0.f;
#pragma unroll 16
    for (int dd = 0; dd < 64; dd++) {
      int d = ks * 64 + dd;
      float w = Wv[d * 256 + col];
      a0 += ysn[0][h][d] * w;
      a1 += ysn[1][h][d] * w;
    }
    part2[ks][col][0] = a0; part2[ks][col][1] = a1;
  }
  __syncthreads();
  if (t < 512) {
    int rp = t >> 8, c = t & 255;
    uls[rp][c] = part2[0][c][rp] + part2[1][c][rp] + part2[2][c][rp] + part2[3][c][rp];
  }
  __syncthreads();
  // ---- Wc
  {
    float a0 = 0.f, a1 = 0.f;
#pragma unroll 16
    for (int dd = 0; dd < 64; dd++) {
      int d = ks * 64 + dd;
      float w = Wc[d * 256 + col];
      a0 += uls[0][d] * w;
      a1 += uls[1][d] * w;
    }
    part2[ks][col][0] = a0; part2[ks][col][1] = a1;
  }
  __syncthreads();
  if (t < 512) {
    int rp = t >> 8, c = t & 255;
    cls[rp][c] = part2[0][c][rp] + part2[1][c][rp] + part2[2][c][rp] + part2[3][c][rp];
  }
  __syncthreads();
  // ---- GRU: 6 gate dot-products x 2 rows in one pass
  {
    float g0a = 0.f, g1a = 0.f, g2a = 0.f, g0b = 0.f, g1b = 0.f, g2b = 0.f;
    float h0a = 0.f, h1a = 0.f, h2a = 0.f, h0b = 0.f, h1b = 0.f, h2b = 0.f;
#pragma unroll 4
    for (int dd = 0; dd < 64; dd++) {
      int d = ks * 64 + dd;
      float c0 = cls[0][d], c1 = cls[1][d];
      float e0 = hls[0][d], e1 = hls[1][d];
      const float* wi = wihT + d * 768 + col;
      const float* wh = whhT + d * 768 + col;
      float wi0 = wi[0], wi1 = wi[256], wi2 = wi[512];
      float wh0 = wh[0], wh1 = wh[256], wh2 = wh[512];
      g0a += c0 * wi0; g1a += c0 * wi1; g2a += c0 * wi2;
      g0b += c1 * wi0; g1b += c1 * wi1; g2b += c1 * wi2;
      h0a += e0 * wh0; h1a += e0 * wh1; h2a += e0 * wh2;
      h0b += e1 * wh0; h1b += e1 * wh1; h2b += e1 * wh2;
    }
    float* p = part6[ks][col];
    p[0] = g0a; p[1] = g0b; p[2] = g1a; p[3] = g1b; p[4] = g2a; p[5] = g2b;
    p[6] = h0a; p[7] = h0b; p[8] = h1a; p[9] = h1b; p[10] = h2a; p[11] = h2b;
  }
  __syncthreads();
  // ---- gates + sn + LN-reduce
  if (t < 512) {
    int rp = t >> 8, c = t & 255;
    float gi0 = part6[0][c][0 + rp] + part6[1][c][0 + rp] + part6[2][c][0 + rp] + part6[3][c][0 + rp] + bih[c];
    float gi1 = part6[0][c][2 + rp] + part6[1][c][2 + rp] + part6[2][c][2 + rp] + part6[3][c][2 + rp] + bih[256 + c];
    float gi2 = part6[0][c][4 + rp] + part6[1][c][4 + rp] + part6[2][c][4 + rp] + part6[3][c][4 + rp] + bih[512 + c];
    float gh0 = part6[0][c][6 + rp] + part6[1][c][6 + rp] + part6[2][c][6 + rp] + part6[3][c][6 + rp] + bhh[c];
    float gh1 = part6[0][c][8 + rp] + part6[1][c][8 + rp] + part6[2][c][8 + rp] + part6[3][c][8 + rp] + bhh[256 + c];
    float gh2 = part6[0][c][10 + rp] + part6[1][c][10 + rp] + part6[2][c][10 + rp] + part6[3][c][10 + rp] + bhh[512 + c];
    float r = 1.f / (1.f + __expf(-(gi0 + gh0)));
    float z = 1.f / (1.f + __expf(-(gi1 + gh1)));
    float nc2 = tanhf(gi2 + r * gh2);
    float sn = (1.f - z) * nc2 + z * hls[rp][c];
    sns[rp][c] = sn;
    float a = sn, bq = sn * sn;
#pragma unroll
    for (int off = 32; off; off >>= 1) { a += __shfl_down(a, off); bq += __shfl_down(bq, off); }
    if ((t & 63) == 0) { red[t >> 6] = a; red[8 + (t >> 6)] = bq; }
  }
  __syncthreads();
  if (t < 512) {
    int rp = t >> 8, c = t & 255;
    float S1 = red[rp * 4] + red[rp * 4 + 1] + red[rp * 4 + 2] + red[rp * 4 + 3];
    float S2 = red[8 + rp * 4] + red[8 + rp * 4 + 1] + red[8 + rp * 4 + 2] + red[8 + rp * 4 + 3];
    float mean = S1 * (1.f / 256.f);
    float var = S2 * (1.f / 256.f) - mean * mean;
    float rstd = rsqrtf(var + LN_EPS);
    lns[rp][c] = (sns[rp][c] - mean) * rstd * g_ml[c] + b_ml[c];
  }
  __syncthreads();
  // ---- W1
  {
    int c5 = t & 511, k5 = t >> 9;
    float a0 = 0.f, a1 = 0.f;
#pragma unroll 16
    for (int dd = 0; dd < 128; dd++) {
      int d = k5 * 128 + dd;
      float w = W1[d * 512 + c5];
      a0 += lns[0][d] * w;
      a1 += lns[1][d] * w;
    }
    part5[k5][c5][0] = a0; part5[k5][c5][1] = a1;
  }
  __syncthreads();
  {
    int rp = t >> 9, c = t & 511;
    hid[rp][c] = fmaxf(part5[0][c][rp] + part5[1][c][rp] + b1[c], 0.f);
  }
  __syncthreads();
  // ---- W2
  {
    float a0 = 0.f, a1 = 0.f;
#pragma unroll 16
    for (int dd = 0; dd < 128; dd++) {
      int d = ks * 128 + dd;
      float w = W2[d * 256 + col];
      a0 += hid[0][d] * w;
      a1 += hid[1][d] * w;
    }
    part2[ks][col][0] = a0; part2[ks][col][1] = a1;
  }
  __syncthreads();
  float outv = 0.f;
  if (t < 512) {
    int rp = t >> 8, c = t & 255;
    outv = sns[rp][c] + b2[c] +
        part2[0][c][rp] + part2[1][c][rp] + part2[2][c][rp] + part2[3][c][rp];
    slots[(2 * i + rp) * 256 + c] = outv;
  }
  // ---- fused t for next iteration
  if (cq) {
    if (t < 512) {
      float a = outv, bq = outv * outv;
#pragma unroll
      for (int off = 32; off; off >>= 1) { a += __shfl_down(a, off); bq += __shfl_down(bq, off); }
      if ((t & 63) == 0) { red[t >> 6] = a; red[8 + (t >> 6)] = bq; }
    }
    __syncthreads();
    if (t < 512) {
      int rp = t >> 8, c = t & 255;
      float S1 = red[rp * 4] + red[rp * 4 + 1] + red[rp * 4 + 2] + red[rp * 4 + 3];
      float S2 = red[8 + rp * 4] + red[8 + rp * 4 + 1] + red[8 + rp * 4 + 2] + red[8 + rp * 4 + 3];
      float mean = S1 * (1.f / 256.f);
      float var = S2 * (1.f / 256.f) - mean * mean;
      float rstd = rsqrtf(var + LN_EPS);
      lns[rp][c] = (outv - mean) * rstd * g_sl[c] + b_sl[c];
    }
    __syncthreads();
    {
      float a0 = 0.f, a1 = 0.f;
#pragma unroll 16
      for (int dd = 0; dd < 64; dd++) {
        int d = ks * 64 + dd;
        float w = Wq[d * 256 + col];
        a0 += lns[0][d] * w;
        a1 += lns[1][d] * w;
      }
      part2[ks][col][0] = a0; part2[ks][col][1] = a1;
    }
    __syncthreads();
    if (t < 512) {
      int rp = t >> 8, c = t & 255;
      uls[rp][c] = part2[0][c][rp] + part2[1][c][rp] + part2[2][c][rp] + part2[3][c][rp];
    }
    __syncthreads();
    int h2 = t >> 8, d2 = t & 255;
    float t0 = 0.f, t1 = 0.f;
#pragma unroll 8
    for (int dp = 0; dp < 64; dp++) {
      float w = (float)WkT16[(h2 * 64 + dp) * 256 + d2];
      t0 += uls[0][h2 * 64 + dp] * w;
      t1 += uls[1][h2 * 64 + dp] * w;
    }
    tq[(b * 32 + h2 * 8 + kp) * 256 + d2] = (f16)(t0 * 0.125f);
    tq[(b * 32 + h2 * 8 + kp + 1) * 256 + d2] = (f16)(t1 * 0.125f);
  }
}

extern "C" void kernel_launch(void* const* d_in, const int* in_sizes, int n_in,
                              void* d_out, int out_size, void* d_ws, size_t ws_size,
                              hipStream_t stream)
{
  const float* inputs = (const float*)d_in[0];
  const float* noise  = (const float*)d_in[1];
  const float* mu     = (const float*)d_in[2];
  const float* lsig   = (const float*)d_in[3];
  const float* g_in   = (const float*)d_in[4];
  const float* b_in   = (const float*)d_in[5];
  const float* g_sl   = (const float*)d_in[6];
  const float* b_sl   = (const float*)d_in[7];
  const float* g_ml   = (const float*)d_in[8];
  const float* b_ml   = (const float*)d_in[9];
  const float* Wq     = (const float*)d_in[10];
  const float* Wk     = (const float*)d_in[11];
  const float* Wv     = (const float*)d_in[12];
  const float* Wc     = (const float*)d_in[13];
  const float* wih    = (const float*)d_in[14];
  const float* whh    = (const float*)d_in[15];
  const float* bih    = (const float*)d_in[16];
  const float* bhh    = (const float*)d_in[17];
  const float* W1     = (const float*)d_in[18];
  const float* b1     = (const float*)d_in[19];
  const float* W2     = (const float*)d_in[20];
  const float* b2     = (const float*)d_in[21];

  char* ws = (char*)d_ws;
  f16*   xln16  = (f16*)(ws);                      //  67,108,864
  f16*   y_part = (f16*)(ws + 67108864);           //  16,777,216
  f16*   tq     = (f16*)(ws + 83886080);           //     524,288
  float* slots  = (float*)(ws + 84410368);         //     262,144
  float* sumsp  = (float*)(ws + 84672512);         //     131,072
  f16*   WkT16  = (f16*)(ws + 84803584);           //     131,072
  float* wihT   = (float*)(ws + 84934656);         //     786,432
  float* whhT   = (float*)(ws + 85721088);         //     786,432  -> end 86,507,520

  init_slots_k<<<256, 256, 0, stream>>>(noise, mu, lsig, slots);
  prep_w_k<<<768, 256, 0, stream>>>(Wk, wih, whh, WkT16, wihT, whhT);
  ln_x_k<<<2048, 256, 0, stream>>>(inputs, g_in, b_in, xln16);
  slot_t_k<<<256, 1024, 0, stream>>>(slots, g_sl, b_sl, Wq, WkT16, tq);
  for (int it = 0; it < 3; ++it) {
    attn_fused_k<<<dim3(32, 32), 256, 0, stream>>>(xln16, tq, y_part, sumsp);
    combine_k<<<128, 1024, 0, stream>>>(y_part, sumsp, slots, Wv, Wc, wihT, whhT,
                                        bih, bhh, g_ml, b_ml, W1, b1, W2, b2,
                                        g_sl, b_sl, Wq, WkT16, tq, (it < 2) ? 1 : 0);
  }
  hipMemcpyAsync(d_out, slots, 65536 * sizeof(float), hipMemcpyDeviceToDevice, stream);
}

// Round 11
// 394.872 us; speedup vs baseline: 1.1908x; 1.1908x over previous
//
#include <hip/hip_runtime.h>
#include <hip/hip_bf16.h>
#include <stdint.h>

typedef unsigned short u16;
typedef _Float16 f16;
typedef __attribute__((ext_vector_type(4))) float f32x4;
typedef __attribute__((ext_vector_type(8))) _Float16 h16x8;
typedef __attribute__((ext_vector_type(4))) _Float16 h16x4;

#define LN_EPS 1e-5f
#define ATT_EPS 1e-8f

// ---------------- init slots: mu + exp(logsigma)*noise ----------------
__global__ __launch_bounds__(256) void init_slots_k(
    const float* __restrict__ noise, const float* __restrict__ mu,
    const float* __restrict__ lsig, float* __restrict__ slots)
{
  int i = blockIdx.x * 256 + threadIdx.x;   // 65536 total
  int d = i & 255;
  slots[i] = mu[d] + __expf(lsig[d]) * noise[i];
}

// ---------------- prep weights: WkT f16, wihT/whhT f32 ----------------
__global__ __launch_bounds__(256) void prep_w_k(
    const float* __restrict__ Wk, const float* __restrict__ wih,
    const float* __restrict__ whh,
    f16* __restrict__ WkT16, float* __restrict__ wihT, float* __restrict__ whhT)
{
  int i = blockIdx.x * 256 + threadIdx.x;   // grid 768 -> 196608
  if (i < 65536) {                           // WkT[c][kd] = Wk[kd][c]
    int c = i >> 8, kd = i & 255;
    WkT16[i] = (f16)Wk[kd * 256 + c];
  }
  int d = i / 768, j = i - d * 768;
  wihT[i] = wih[j * 256 + d];
  whhT[i] = whh[j * 256 + d];
}

// ---------------- pure LN pass: xln16 = LN(inputs) as f16 ----------------
// grid 2048, block 256 (4 waves): one wave per row, 16 rows/wave
__global__ __launch_bounds__(256) void ln_x_k(
    const float* __restrict__ inputs, const float* __restrict__ g_in,
    const float* __restrict__ b_in, f16* __restrict__ xln16)
{
  int t = threadIdx.x, w = t >> 6, l = t & 63;
  float4 gv = *(const float4*)(g_in + l * 4);
  float4 bv = *(const float4*)(b_in + l * 4);
  long row0 = (long)blockIdx.x * 64 + w * 16;
#pragma unroll 2
  for (int i = 0; i < 16; i++) {
    long r = row0 + i;
    float4 x = *(const float4*)(inputs + r * 256 + l * 4);
    float s1 = x.x + x.y + x.z + x.w;
    float s2 = x.x * x.x + x.y * x.y + x.z * x.z + x.w * x.w;
#pragma unroll
    for (int off = 1; off < 64; off <<= 1) {
      s1 += __shfl_xor(s1, off);
      s2 += __shfl_xor(s2, off);
    }
    float m = s1 * (1.f / 256.f);
    float var = s2 * (1.f / 256.f) - m * m;
    float rs = rsqrtf(var + LN_EPS);
    h16x4 o;
    o[0] = (f16)((x.x - m) * rs * gv.x + bv.x);
    o[1] = (f16)((x.y - m) * rs * gv.y + bv.y);
    o[2] = (f16)((x.z - m) * rs * gv.z + bv.z);
    o[3] = (f16)((x.w - m) * rs * gv.w + bv.w);
    *(h16x4*)(xln16 + r * 256 + l * 4) = o;
  }
}

// ---------------- t = (LN(slots)@Wq) projected through Wk heads, x SCALE ----
// grid 256 (one slot row per block), block 1024 (iter-0 only)
__global__ __launch_bounds__(1024) void slot_t_k(
    const float* __restrict__ slots, const float* __restrict__ g_sl,
    const float* __restrict__ b_sl, const float* __restrict__ Wq,
    const f16* __restrict__ WkT16, f16* __restrict__ tq)
{
  __shared__ float ln[256];
  __shared__ float qs[256];
  __shared__ float part[4][256];
  __shared__ float red[8];
  int t = threadIdx.x;
  int i = blockIdx.x;
  if (t < 256) {
    float x = slots[i * 256 + t];
    float a = x, bq = x * x;
#pragma unroll
    for (int off = 32; off; off >>= 1) { a += __shfl_down(a, off); bq += __shfl_down(bq, off); }
    if ((t & 63) == 0) { red[t >> 6] = a; red[4 + (t >> 6)] = bq; }
  }
  __syncthreads();
  if (t < 256) {
    float x = slots[i * 256 + t];
    float S1 = red[0] + red[1] + red[2] + red[3];
    float S2 = red[4] + red[5] + red[6] + red[7];
    float m = S1 * (1.f / 256.f);
    float var = S2 * (1.f / 256.f) - m * m;
    float rstd = rsqrtf(var + LN_EPS);
    ln[t] = (x - m) * rstd * g_sl[t] + b_sl[t];
  }
  __syncthreads();
  int col = t & 255, ks = t >> 8;
  float acc = 0.f;
#pragma unroll 16
  for (int dd = 0; dd < 64; dd++) {
    int d = ks * 64 + dd;
    acc += ln[d] * Wq[d * 256 + col];
  }
  part[ks][col] = acc;
  __syncthreads();
  if (t < 256) qs[t] = part[0][t] + part[1][t] + part[2][t] + part[3][t];
  __syncthreads();
  int h = t >> 8, d2 = t & 255;
  float tt = 0.f;
#pragma unroll 8
  for (int dp = 0; dp < 64; dp++)
    tt += qs[h * 64 + dp] * (float)WkT16[(h * 64 + dp) * 256 + d2];
  tq[((i >> 3) * 32 + h * 8 + (i & 7)) * 256 + d2] = (f16)(tt * 0.125f);
}

// ---------------- fused attn: MFMA dots + shuffle softmax + MFMA PV ----------
// grid (32 b, 32 nchunk of 128 n), block 256 (4 waves). 2 subtiles of 64 n.
__global__ __launch_bounds__(256, 3) void attn_fused_k(
    const f16* __restrict__ xln16, const f16* __restrict__ tq,
    f16* __restrict__ y_part, float* __restrict__ sums_part)
{
  __shared__ u16 xsT[256 * 64];      // 32KB: addr = d*128 + ((n8 ^ (d&7))<<4)
  __shared__ u16 attT[32 * 64];      // 4KB:  addr = hs*128 + ((n8 ^ (hs&7))<<4)
  __shared__ float asum_s[4][32];
  int b = blockIdx.x, nc = blockIdx.y, t = threadIdx.x;
  int nb = nc * 128;
  int w = t >> 6, l = t & 63;
  int lc = l & 15, lg = l >> 4;
  h16x8 tb0[8], tb1[8];
#pragma unroll
  for (int k0 = 0; k0 < 8; k0++) {
    tb0[k0] = *(const h16x8*)(tq + (b * 32 + lc) * 256 + k0 * 32 + lg * 8);
    tb1[k0] = *(const h16x8*)(tq + (b * 32 + lc + 16) * 256 + k0 * 32 + lg * 8);
  }
  f32x4 acc0[4], acc1[4];
#pragma unroll
  for (int dt = 0; dt < 4; dt++) { acc0[dt] = (f32x4){0,0,0,0}; acc1[dt] = (f32x4){0,0,0,0}; }
  float as0 = 0.f, as1 = 0.f;

  for (int sub = 0; sub < 2; sub++) {
    __syncthreads();
    {
      int nl8 = t >> 5, dchunk = t & 31;
      const f16* gp = xln16 + ((long)(b * 4096 + nb + sub * 64 + nl8 * 8)) * 256 + dchunk * 8;
      h16x8 v0 = *(const h16x8*)(gp);
      h16x8 v1 = *(const h16x8*)(gp + 256);
      h16x8 v2 = *(const h16x8*)(gp + 512);
      h16x8 v3 = *(const h16x8*)(gp + 768);
      h16x8 v4 = *(const h16x8*)(gp + 1024);
      h16x8 v5 = *(const h16x8*)(gp + 1280);
      h16x8 v6 = *(const h16x8*)(gp + 1536);
      h16x8 v7 = *(const h16x8*)(gp + 1792);
#pragma unroll
      for (int j = 0; j < 8; j++) {
        h16x8 o;
        o[0] = v0[j]; o[1] = v1[j]; o[2] = v2[j]; o[3] = v3[j];
        o[4] = v4[j]; o[5] = v5[j]; o[6] = v6[j]; o[7] = v7[j];
        int d = dchunk * 8 + j;
        *(h16x8*)((char*)xsT + d * 128 + ((nl8 ^ j) << 4)) = o;
      }
    }
    f32x4 D0 = {0,0,0,0}, D1 = {0,0,0,0};
    {
      const f16* ga = xln16 + ((long)(b * 4096 + nb + sub * 64 + w * 16 + lc)) * 256 + lg * 8;
#pragma unroll
      for (int k0 = 0; k0 < 8; k0++) {
        h16x8 af = *(const h16x8*)(ga + k0 * 32);
        D0 = __builtin_amdgcn_mfma_f32_16x16x32_f16(af, tb0[k0], D0, 0, 0, 0);
        D1 = __builtin_amdgcn_mfma_f32_16x16x32_f16(af, tb1[k0], D1, 0, 0, 0);
      }
    }
    h16x4 pk0, pk1;
#pragma unroll
    for (int r = 0; r < 4; r++) {
      float d0 = D0[r], d1 = D1[r];
      float m0 = d0, m1 = d1;
      m0 = fmaxf(m0, __shfl_xor(m0, 1)); m0 = fmaxf(m0, __shfl_xor(m0, 2)); m0 = fmaxf(m0, __shfl_xor(m0, 4));
      m1 = fmaxf(m1, __shfl_xor(m1, 1)); m1 = fmaxf(m1, __shfl_xor(m1, 2)); m1 = fmaxf(m1, __shfl_xor(m1, 4));
      float e0 = __expf(d0 - m0), e1 = __expf(d1 - m1);
      float s0 = e0, s1 = e1;
      s0 += __shfl_xor(s0, 1); s0 += __shfl_xor(s0, 2); s0 += __shfl_xor(s0, 4);
      s1 += __shfl_xor(s1, 1); s1 += __shfl_xor(s1, 2); s1 += __shfl_xor(s1, 4);
      f16 a0h = (f16)(e0 / s0), a1h = (f16)(e1 / s1);
      as0 += (float)a0h; as1 += (float)a1h;
      pk0[r] = a0h; pk1[r] = a1h;
    }
    {
      int slot = w * 2 + (lg >> 1);
      int boff = (lg & 1) * 8;
      *(h16x4*)((char*)attT + lc * 128 + ((slot ^ (lc & 7)) << 4) + boff) = pk0;
      *(h16x4*)((char*)attT + (lc + 16) * 128 + ((slot ^ (lc & 7)) << 4) + boff) = pk1;
    }
    __syncthreads();
    h16x8 A00, A01, A10, A11;
    {
      int hs0 = lc, hs1 = 16 + lc, sw = lc & 7;
      A00 = *(const h16x8*)((char*)attT + hs0 * 128 + ((lg ^ sw) << 4));
      A01 = *(const h16x8*)((char*)attT + hs0 * 128 + (((4 + lg) ^ sw) << 4));
      A10 = *(const h16x8*)((char*)attT + hs1 * 128 + ((lg ^ sw) << 4));
      A11 = *(const h16x8*)((char*)attT + hs1 * 128 + (((4 + lg) ^ sw) << 4));
    }
#pragma unroll
    for (int dt = 0; dt < 4; dt++) {
      int d = w * 64 + dt * 16 + lc;
      h16x8 B0 = *(const h16x8*)((char*)xsT + d * 128 + ((lg ^ (d & 7)) << 4));
      h16x8 B1 = *(const h16x8*)((char*)xsT + d * 128 + (((4 + lg) ^ (d & 7)) << 4));
      acc0[dt] = __builtin_amdgcn_mfma_f32_16x16x32_f16(A00, B0, acc0[dt], 0, 0, 0);
      acc0[dt] = __builtin_amdgcn_mfma_f32_16x16x32_f16(A01, B1, acc0[dt], 0, 0, 0);
      acc1[dt] = __builtin_amdgcn_mfma_f32_16x16x32_f16(A10, B0, acc1[dt], 0, 0, 0);
      acc1[dt] = __builtin_amdgcn_mfma_f32_16x16x32_f16(A11, B1, acc1[dt], 0, 0, 0);
    }
  }
  as0 += __shfl_xor(as0, 16); as0 += __shfl_xor(as0, 32);
  as1 += __shfl_xor(as1, 16); as1 += __shfl_xor(as1, 32);
  if (l < 16) { asum_s[w][l] = as0; asum_s[w][l + 16] = as1; }
  __syncthreads();
  if (t < 32)
    sums_part[(nc * 32 + b) * 32 + t] =
        asum_s[0][t] + asum_s[1][t] + asum_s[2][t] + asum_s[3][t];
  long ybase = ((long)(nc * 32 + b) * 32) * 256;
#pragma unroll
  for (int reg = 0; reg < 4; reg++) {
    int hsA = lg * 4 + reg;
#pragma unroll
    for (int dt = 0; dt < 4; dt++) {
      int d = w * 64 + dt * 16 + lc;
      y_part[ybase + hsA * 256 + d] = (f16)acc0[dt][reg];
      y_part[ybase + (16 + hsA) * 256 + d] = (f16)acc1[dt][reg];
    }
  }
}

// ---------------- combine v3: grid 256, inline partial-sums, 11 barriers ------
__global__ __launch_bounds__(1024) void combine_k(
    const f16* __restrict__ y_part, const float* __restrict__ sums_part,
    float* __restrict__ slots, const float* __restrict__ Wv,
    const float* __restrict__ Wc, const float* __restrict__ wihT,
    const float* __restrict__ whhT, const float* __restrict__ bih,
    const float* __restrict__ bhh, const float* __restrict__ g_ml,
    const float* __restrict__ b_ml, const float* __restrict__ W1,
    const float* __restrict__ b1, const float* __restrict__ W2,
    const float* __restrict__ b2, const float* __restrict__ g_sl,
    const float* __restrict__ b_sl, const float* __restrict__ Wq,
    const f16* __restrict__ WkT16, f16* __restrict__ tq, int cq)
{
  __shared__ float ysn[4][256];
  __shared__ float hls[256], sns[256], lns[256];
  __shared__ float pA[4][256], pB[4][256];
  __shared__ float part6[4][256][7];   // 6 used, 7 for bank spread
  __shared__ float part5[2][512];
  __shared__ float red[8];
  int t = threadIdx.x;
  int i = blockIdx.x;
  int b = i >> 3, k = i & 7;
  // ---- S1: y-reduce + normalize
  {
    int j = t >> 8, d = t & 255;   // j = head
    float den = ATT_EPS, yv = 0.f;
#pragma unroll 8
    for (int ncq = 0; ncq < 32; ncq++) {
      int hsrow = (ncq * 32 + b) * 32 + j * 8 + k;
      den += sums_part[hsrow];
      yv += (float)y_part[(long)hsrow * 256 + d];
    }
    ysn[j][d] = yv / den;
    if (t < 256) hls[t] = slots[i * 256 + t];
  }
  __syncthreads();
  int col = t & 255, ks = t >> 8;
  // ---- S2: Wv (block-diagonal per head)
  {
    int h = col >> 6;
    float acc = 0.f;
#pragma unroll 16
    for (int dd = 0; dd < 64; dd++) {
      int d = ks * 64 + dd;
      acc += ysn[h][d] * Wv[d * 256 + col];
    }
    pA[ks][col] = acc;
  }
  __syncthreads();
  // ---- S3: Wc (inline uls from pA)
  {
    float acc = 0.f;
#pragma unroll 16
    for (int dd = 0; dd < 64; dd++) {
      int d = ks * 64 + dd;
      float u = pA[0][d] + pA[1][d] + pA[2][d] + pA[3][d];
      acc += u * Wc[d * 256 + col];
    }
    pB[ks][col] = acc;
  }
  __syncthreads();
  // ---- S4: GRU 6 dot-products (inline cls from pB)
  {
    float a0 = 0.f, a1 = 0.f, a2 = 0.f, h0 = 0.f, h1 = 0.f, h2 = 0.f;
#pragma unroll 4
    for (int dd = 0; dd < 64; dd++) {
      int d = ks * 64 + dd;
      float c = pB[0][d] + pB[1][d] + pB[2][d] + pB[3][d];
      float hh = hls[d];
      const float* wi = wihT + d * 768 + col;
      const float* wh = whhT + d * 768 + col;
      a0 += c * wi[0]; a1 += c * wi[256]; a2 += c * wi[512];
      h0 += hh * wh[0]; h1 += hh * wh[256]; h2 += hh * wh[512];
    }
    part6[ks][col][0] = a0; part6[ks][col][1] = a1; part6[ks][col][2] = a2;
    part6[ks][col][3] = h0; part6[ks][col][4] = h1; part6[ks][col][5] = h2;
  }
  __syncthreads();
  // ---- S5: gates + sn + LN-reduce
  if (t < 256) {
    float gi0 = part6[0][t][0] + part6[1][t][0] + part6[2][t][0] + part6[3][t][0] + bih[t];
    float gi1 = part6[0][t][1] + part6[1][t][1] + part6[2][t][1] + part6[3][t][1] + bih[256 + t];
    float gi2 = part6[0][t][2] + part6[1][t][2] + part6[2][t][2] + part6[3][t][2] + bih[512 + t];
    float gh0 = part6[0][t][3] + part6[1][t][3] + part6[2][t][3] + part6[3][t][3] + bhh[t];
    float gh1 = part6[0][t][4] + part6[1][t][4] + part6[2][t][4] + part6[3][t][4] + bhh[256 + t];
    float gh2 = part6[0][t][5] + part6[1][t][5] + part6[2][t][5] + part6[3][t][5] + bhh[512 + t];
    float r = 1.f / (1.f + __expf(-(gi0 + gh0)));
    float z = 1.f / (1.f + __expf(-(gi1 + gh1)));
    float nc2 = tanhf(gi2 + r * gh2);
    float sn = (1.f - z) * nc2 + z * hls[t];
    sns[t] = sn;
    float a = sn, bq = sn * sn;
#pragma unroll
    for (int off = 32; off; off >>= 1) { a += __shfl_down(a, off); bq += __shfl_down(bq, off); }
    if ((t & 63) == 0) { red[t >> 6] = a; red[4 + (t >> 6)] = bq; }
  }
  __syncthreads();
  // ---- S6: lns
  if (t < 256) {
    float S1 = red[0] + red[1] + red[2] + red[3];
    float S2 = red[4] + red[5] + red[6] + red[7];
    float mean = S1 * (1.f / 256.f);
    float var = S2 * (1.f / 256.f) - mean * mean;
    float rstd = rsqrtf(var + LN_EPS);
    lns[t] = (sns[t] - mean) * rstd * g_ml[t] + b_ml[t];
  }
  __syncthreads();
  // ---- S7: W1
  {
    int c5 = t & 511, k5 = t >> 9;
    float acc = 0.f;
#pragma unroll 16
    for (int dd = 0; dd < 128; dd++) {
      int d = k5 * 128 + dd;
      acc += lns[d] * W1[d * 512 + c5];
    }
    part5[k5][c5] = acc;
  }
  __syncthreads();
  // ---- S8: W2 (inline hid from part5)
  {
    float acc = 0.f;
#pragma unroll 16
    for (int dd = 0; dd < 128; dd++) {
      int d = ks * 128 + dd;
      float hd = fmaxf(part5[0][d] + part5[1][d] + b1[d], 0.f);
      acc += hd * W2[d * 256 + col];
    }
    pA[ks][col] = acc;
  }
  __syncthreads();
  // ---- S9: outv (inline from pA) + store
  float outv = 0.f;
  if (t < 256) {
    outv = sns[t] + b2[t] + pA[0][t] + pA[1][t] + pA[2][t] + pA[3][t];
    slots[i * 256 + t] = outv;
  }
  if (!cq) return;   // uniform across block
  if (t < 256) {
    float a = outv, bq = outv * outv;
#pragma unroll
    for (int off = 32; off; off >>= 1) { a += __shfl_down(a, off); bq += __shfl_down(bq, off); }
    if ((t & 63) == 0) { red[t >> 6] = a; red[4 + (t >> 6)] = bq; }
  }
  __syncthreads();
  // ---- S10: lns2
  if (t < 256) {
    float S1 = red[0] + red[1] + red[2] + red[3];
    float S2 = red[4] + red[5] + red[6] + red[7];
    float mean = S1 * (1.f / 256.f);
    float var = S2 * (1.f / 256.f) - mean * mean;
    float rstd = rsqrtf(var + LN_EPS);
    lns[t] = (outv - mean) * rstd * g_sl[t] + b_sl[t];
  }
  __syncthreads();
  // ---- S11: Wq
  {
    float acc = 0.f;
#pragma unroll 16
    for (int dd = 0; dd < 64; dd++) {
      int d = ks * 64 + dd;
      acc += lns[d] * Wq[d * 256 + col];
    }
    pB[ks][col] = acc;
  }
  __syncthreads();
  // ---- S12: Wk head-projection (inline uls2 from pB)
  {
    int h2 = t >> 8, d2 = t & 255;
    float tt = 0.f;
#pragma unroll 8
    for (int dp = 0; dp < 64; dp++) {
      int hd = h2 * 64 + dp;
      float u = pB[0][hd] + pB[1][hd] + pB[2][hd] + pB[3][hd];
      tt += u * (float)WkT16[hd * 256 + d2];
    }
    tq[(b * 32 + h2 * 8 + k) * 256 + d2] = (f16)(tt * 0.125f);
  }
}

extern "C" void kernel_launch(void* const* d_in, const int* in_sizes, int n_in,
                              void* d_out, int out_size, void* d_ws, size_t ws_size,
                              hipStream_t stream)
{
  const float* inputs = (const float*)d_in[0];
  const float* noise  = (const float*)d_in[1];
  const float* mu     = (const float*)d_in[2];
  const float* lsig   = (const float*)d_in[3];
  const float* g_in   = (const float*)d_in[4];
  const float* b_in   = (const float*)d_in[5];
  const float* g_sl   = (const float*)d_in[6];
  const float* b_sl   = (const float*)d_in[7];
  const float* g_ml   = (const float*)d_in[8];
  const float* b_ml   = (const float*)d_in[9];
  const float* Wq     = (const float*)d_in[10];
  const float* Wk     = (const float*)d_in[11];
  const float* Wv     = (const float*)d_in[12];
  const float* Wc     = (const float*)d_in[13];
  const float* wih    = (const float*)d_in[14];
  const float* whh    = (const float*)d_in[15];
  const float* bih    = (const float*)d_in[16];
  const float* bhh    = (const float*)d_in[17];
  const float* W1     = (const float*)d_in[18];
  const float* b1     = (const float*)d_in[19];
  const float* W2     = (const float*)d_in[20];
  const float* b2     = (const float*)d_in[21];

  char* ws = (char*)d_ws;
  f16*   xln16  = (f16*)(ws);                      //  67,108,864
  f16*   y_part = (f16*)(ws + 67108864);           //  16,777,216
  f16*   tq     = (f16*)(ws + 83886080);           //     524,288
  float* slots  = (float*)(ws + 84410368);         //     262,144
  float* sumsp  = (float*)(ws + 84672512);         //     131,072
  f16*   WkT16  = (f16*)(ws + 84803584);           //     131,072
  float* wihT   = (float*)(ws + 84934656);         //     786,432
  float* whhT   = (float*)(ws + 85721088);         //     786,432  -> end 86,507,520

  init_slots_k<<<256, 256, 0, stream>>>(noise, mu, lsig, slots);
  prep_w_k<<<768, 256, 0, stream>>>(Wk, wih, whh, WkT16, wihT, whhT);
  ln_x_k<<<2048, 256, 0, stream>>>(inputs, g_in, b_in, xln16);
  slot_t_k<<<256, 1024, 0, stream>>>(slots, g_sl, b_sl, Wq, WkT16, tq);
  for (int it = 0; it < 3; ++it) {
    attn_fused_k<<<dim3(32, 32), 256, 0, stream>>>(xln16, tq, y_part, sumsp);
    combine_k<<<256, 1024, 0, stream>>>(y_part, sumsp, slots, Wv, Wc, wihT, whhT,
                                        bih, bhh, g_ml, b_ml, W1, b1, W2, b2,
                                        g_sl, b_sl, Wq, WkT16, tq, (it < 2) ? 1 : 0);
  }
  hipMemcpyAsync(d_out, slots, 65536 * sizeof(float), hipMemcpyDeviceToDevice, stream);
}

// Round 13
// 282.418 us; speedup vs baseline: 1.6649x; 1.3982x over previous
//
#include <hip/hip_runtime.h>
#include <hip/hip_bf16.h>
#include <stdint.h>

typedef unsigned short u16;
typedef _Float16 f16;
typedef __attribute__((ext_vector_type(4))) float f32x4;
typedef __attribute__((ext_vector_type(8))) _Float16 h16x8;
typedef __attribute__((ext_vector_type(4))) _Float16 h16x4;

#define LN_EPS 1e-5f
#define ATT_EPS 1e-8f

// ---------------- init slots: mu + exp(logsigma)*noise ----------------
__global__ __launch_bounds__(256) void init_slots_k(
    const float* __restrict__ noise, const float* __restrict__ mu,
    const float* __restrict__ lsig, float* __restrict__ slots)
{
  int i = blockIdx.x * 256 + threadIdx.x;   // 65536 total
  int d = i & 255;
  slots[i] = mu[d] + __expf(lsig[d]) * noise[i];
}

// ---------------- prep weights: WkT f16, whhT f32 ----------------
__global__ __launch_bounds__(256) void prep_w_k(
    const float* __restrict__ Wk, const float* __restrict__ whh,
    f16* __restrict__ WkT16, float* __restrict__ whhT)
{
  int i = blockIdx.x * 256 + threadIdx.x;   // grid 768 -> 196608
  if (i < 65536) {                           // WkT[c][kd] = Wk[kd][c]
    int c = i >> 8, kd = i & 255;
    WkT16[i] = (f16)Wk[kd * 256 + c];
  }
  int d = i / 768, j = i - d * 768;
  whhT[i] = whh[j * 256 + d];
}

// ---------------- prep F = Wc @ wih^T, stored as fihT[d][j] (256 x 768) ------
// grid (16 dblk, 24 jblk), block 256. Tile 16 d x 32 j, full c=256 in LDS.
__global__ __launch_bounds__(256) void prep_f_k(
    const float* __restrict__ Wc, const float* __restrict__ wih,
    float* __restrict__ fihT)
{
  __shared__ float wcs[16][257];
  __shared__ float ws[32][257];
  int t = threadIdx.x;
  int d0 = blockIdx.x * 16, j0 = blockIdx.y * 32;
  for (int i = t; i < 4096; i += 256) {
    int r = i >> 8, c = i & 255;
    wcs[r][c] = Wc[(d0 + r) * 256 + c];
  }
  for (int i = t; i < 8192; i += 256) {
    int r = i >> 8, c = i & 255;
    ws[r][c] = wih[(j0 + r) * 256 + c];
  }
  __syncthreads();
  int dl = t & 15, jp = t >> 4;
  float a0 = 0.f, a1 = 0.f;
#pragma unroll 8
  for (int c = 0; c < 256; c++) {
    float wv = wcs[dl][c];
    a0 += wv * ws[jp][c];
    a1 += wv * ws[jp + 16][c];
  }
  fihT[(d0 + dl) * 768 + j0 + jp] = a0;
  fihT[(d0 + dl) * 768 + j0 + jp + 16] = a1;
}

// ---------------- pure LN pass: xln16 = LN(inputs) as f16 ----------------
// grid 2048, block 256 (4 waves): one wave per row, 16 rows/wave
__global__ __launch_bounds__(256) void ln_x_k(
    const float* __restrict__ inputs, const float* __restrict__ g_in,
    const float* __restrict__ b_in, f16* __restrict__ xln16)
{
  int t = threadIdx.x, w = t >> 6, l = t & 63;
  float4 gv = *(const float4*)(g_in + l * 4);
  float4 bv = *(const float4*)(b_in + l * 4);
  long row0 = (long)blockIdx.x * 64 + w * 16;
#pragma unroll 2
  for (int i = 0; i < 16; i++) {
    long r = row0 + i;
    float4 x = *(const float4*)(inputs + r * 256 + l * 4);
    float s1 = x.x + x.y + x.z + x.w;
    float s2 = x.x * x.x + x.y * x.y + x.z * x.z + x.w * x.w;
#pragma unroll
    for (int off = 1; off < 64; off <<= 1) {
      s1 += __shfl_xor(s1, off);
      s2 += __shfl_xor(s2, off);
    }
    float m = s1 * (1.f / 256.f);
    float var = s2 * (1.f / 256.f) - m * m;
    float rs = rsqrtf(var + LN_EPS);
    h16x4 o;
    o[0] = (f16)((x.x - m) * rs * gv.x + bv.x);
    o[1] = (f16)((x.y - m) * rs * gv.y + bv.y);
    o[2] = (f16)((x.z - m) * rs * gv.z + bv.z);
    o[3] = (f16)((x.w - m) * rs * gv.w + bv.w);
    *(h16x4*)(xln16 + r * 256 + l * 4) = o;
  }
}

// ---------------- t = (LN(slots)@Wq) projected through Wk heads, x SCALE ----
// grid 256 (one slot row per block), block 1024 (iter-0 only)
__global__ __launch_bounds__(1024) void slot_t_k(
    const float* __restrict__ slots, const float* __restrict__ g_sl,
    const float* __restrict__ b_sl, const float* __restrict__ Wq,
    const f16* __restrict__ WkT16, f16* __restrict__ tq)
{
  __shared__ float ln[256];
  __shared__ float qs[256];
  __shared__ float part[4][256];
  __shared__ float red[8];
  int t = threadIdx.x;
  int i = blockIdx.x;
  if (t < 256) {
    float x = slots[i * 256 + t];
    float a = x, bq = x * x;
#pragma unroll
    for (int off = 32; off; off >>= 1) { a += __shfl_down(a, off); bq += __shfl_down(bq, off); }
    if ((t & 63) == 0) { red[t >> 6] = a; red[4 + (t >> 6)] = bq; }
  }
  __syncthreads();
  if (t < 256) {
    float x = slots[i * 256 + t];
    float S1 = red[0] + red[1] + red[2] + red[3];
    float S2 = red[4] + red[5] + red[6] + red[7];
    float m = S1 * (1.f / 256.f);
    float var = S2 * (1.f / 256.f) - m * m;
    float rstd = rsqrtf(var + LN_EPS);
    ln[t] = (x - m) * rstd * g_sl[t] + b_sl[t];
  }
  __syncthreads();
  int col = t & 255, ks = t >> 8;
  float acc = 0.f;
#pragma unroll 16
  for (int dd = 0; dd < 64; dd++) {
    int d = ks * 64 + dd;
    acc += ln[d] * Wq[d * 256 + col];
  }
  part[ks][col] = acc;
  __syncthreads();
  if (t < 256) qs[t] = part[0][t] + part[1][t] + part[2][t] + part[3][t];
  __syncthreads();
  int h = t >> 8, d2 = t & 255;
  float tt = 0.f;
#pragma unroll 8
  for (int dp = 0; dp < 64; dp++)
    tt += qs[h * 64 + dp] * (float)WkT16[(h * 64 + dp) * 256 + d2];
  tq[((i >> 3) * 32 + h * 8 + (i & 7)) * 256 + d2] = (f16)(tt * 0.125f);
}

// ---------------- fused attn: MFMA dots + shuffle softmax + MFMA PV ----------
// grid (32 b, 32 nchunk of 128 n), block 256 (4 waves). 2 subtiles of 64 n.
__global__ __launch_bounds__(256, 3) void attn_fused_k(
    const f16* __restrict__ xln16, const f16* __restrict__ tq,
    f16* __restrict__ y_part, float* __restrict__ sums_part)
{
  __shared__ u16 xsT[256 * 64];      // 32KB: addr = d*128 + ((n8 ^ (d&7))<<4)
  __shared__ u16 attT[32 * 64];      // 4KB:  addr = hs*128 + ((n8 ^ (hs&7))<<4)
  __shared__ float asum_s[4][32];
  int b = blockIdx.x, nc = blockIdx.y, t = threadIdx.x;
  int nb = nc * 128;
  int w = t >> 6, l = t & 63;
  int lc = l & 15, lg = l >> 4;
  h16x8 tb0[8], tb1[8];
#pragma unroll
  for (int k0 = 0; k0 < 8; k0++) {
    tb0[k0] = *(const h16x8*)(tq + (b * 32 + lc) * 256 + k0 * 32 + lg * 8);
    tb1[k0] = *(const h16x8*)(tq + (b * 32 + lc + 16) * 256 + k0 * 32 + lg * 8);
  }
  f32x4 acc0[4], acc1[4];
#pragma unroll
  for (int dt = 0; dt < 4; dt++) { acc0[dt] = (f32x4){0,0,0,0}; acc1[dt] = (f32x4){0,0,0,0}; }
  float as0 = 0.f, as1 = 0.f;

  for (int sub = 0; sub < 2; sub++) {
    __syncthreads();
    {
      int nl8 = t >> 5, dchunk = t & 31;
      const f16* gp = xln16 + ((long)(b * 4096 + nb + sub * 64 + nl8 * 8)) * 256 + dchunk * 8;
      h16x8 v0 = *(const h16x8*)(gp);
      h16x8 v1 = *(const h16x8*)(gp + 256);
      h16x8 v2 = *(const h16x8*)(gp + 512);
      h16x8 v3 = *(const h16x8*)(gp + 768);
      h16x8 v4 = *(const h16x8*)(gp + 1024);
      h16x8 v5 = *(const h16x8*)(gp + 1280);
      h16x8 v6 = *(const h16x8*)(gp + 1536);
      h16x8 v7 = *(const h16x8*)(gp + 1792);
#pragma unroll
      for (int j = 0; j < 8; j++) {
        h16x8 o;
        o[0] = v0[j]; o[1] = v1[j]; o[2] = v2[j]; o[3] = v3[j];
        o[4] = v4[j]; o[5] = v5[j]; o[6] = v6[j]; o[7] = v7[j];
        int d = dchunk * 8 + j;
        *(h16x8*)((char*)xsT + d * 128 + ((nl8 ^ j) << 4)) = o;
      }
    }
    f32x4 D0 = {0,0,0,0}, D1 = {0,0,0,0};
    {
      const f16* ga = xln16 + ((long)(b * 4096 + nb + sub * 64 + w * 16 + lc)) * 256 + lg * 8;
#pragma unroll
      for (int k0 = 0; k0 < 8; k0++) {
        h16x8 af = *(const h16x8*)(ga + k0 * 32);
        D0 = __builtin_amdgcn_mfma_f32_16x16x32_f16(af, tb0[k0], D0, 0, 0, 0);
        D1 = __builtin_amdgcn_mfma_f32_16x16x32_f16(af, tb1[k0], D1, 0, 0, 0);
      }
    }
    h16x4 pk0, pk1;
#pragma unroll
    for (int r = 0; r < 4; r++) {
      float d0 = D0[r], d1 = D1[r];
      float m0 = d0, m1 = d1;
      m0 = fmaxf(m0, __shfl_xor(m0, 1)); m0 = fmaxf(m0, __shfl_xor(m0, 2)); m0 = fmaxf(m0, __shfl_xor(m0, 4));
      m1 = fmaxf(m1, __shfl_xor(m1, 1)); m1 = fmaxf(m1, __shfl_xor(m1, 2)); m1 = fmaxf(m1, __shfl_xor(m1, 4));
      float e0 = __expf(d0 - m0), e1 = __expf(d1 - m1);
      float s0 = e0, s1 = e1;
      s0 += __shfl_xor(s0, 1); s0 += __shfl_xor(s0, 2); s0 += __shfl_xor(s0, 4);
      s1 += __shfl_xor(s1, 1); s1 += __shfl_xor(s1, 2); s1 += __shfl_xor(s1, 4);
      f16 a0h = (f16)(e0 / s0), a1h = (f16)(e1 / s1);
      as0 += (float)a0h; as1 += (float)a1h;
      pk0[r] = a0h; pk1[r] = a1h;
    }
    {
      int slot = w * 2 + (lg >> 1);
      int boff = (lg & 1) * 8;
      *(h16x4*)((char*)attT + lc * 128 + ((slot ^ (lc & 7)) << 4) + boff) = pk0;
      *(h16x4*)((char*)attT + (lc + 16) * 128 + ((slot ^ (lc & 7)) << 4) + boff) = pk1;
    }
    __syncthreads();
    h16x8 A00, A01, A10, A11;
    {
      int hs0 = lc, hs1 = 16 + lc, sw = lc & 7;
      A00 = *(const h16x8*)((char*)attT + hs0 * 128 + ((lg ^ sw) << 4));
      A01 = *(const h16x8*)((char*)attT + hs0 * 128 + (((4 + lg) ^ sw) << 4));
      A10 = *(const h16x8*)((char*)attT + hs1 * 128 + ((lg ^ sw) << 4));
      A11 = *(const h16x8*)((char*)attT + hs1 * 128 + (((4 + lg) ^ sw) << 4));
    }
#pragma unroll
    for (int dt = 0; dt < 4; dt++) {
      int d = w * 64 + dt * 16 + lc;
      h16x8 B0 = *(const h16x8*)((char*)xsT + d * 128 + ((lg ^ (d & 7)) << 4));
      h16x8 B1 = *(const h16x8*)((char*)xsT + d * 128 + (((4 + lg) ^ (d & 7)) << 4));
      acc0[dt] = __builtin_amdgcn_mfma_f32_16x16x32_f16(A00, B0, acc0[dt], 0, 0, 0);
      acc0[dt] = __builtin_amdgcn_mfma_f32_16x16x32_f16(A01, B1, acc0[dt], 0, 0, 0);
      acc1[dt] = __builtin_amdgcn_mfma_f32_16x16x32_f16(A10, B0, acc1[dt], 0, 0, 0);
      acc1[dt] = __builtin_amdgcn_mfma_f32_16x16x32_f16(A11, B1, acc1[dt], 0, 0, 0);
    }
  }
  as0 += __shfl_xor(as0, 16); as0 += __shfl_xor(as0, 32);
  as1 += __shfl_xor(as1, 16); as1 += __shfl_xor(as1, 32);
  if (l < 16) { asum_s[w][l] = as0; asum_s[w][l + 16] = as1; }
  __syncthreads();
  if (t < 32)
    sums_part[(nc * 32 + b) * 32 + t] =
        asum_s[0][t] + asum_s[1][t] + asum_s[2][t] + asum_s[3][t];
  long ybase = ((long)(nc * 32 + b) * 32) * 256;
#pragma unroll
  for (int reg = 0; reg < 4; reg++) {
    int hsA = lg * 4 + reg;
#pragma unroll
    for (int dt = 0; dt < 4; dt++) {
      int d = w * 64 + dt * 16 + lc;
      y_part[ybase + hsA * 256 + d] = (f16)acc0[dt][reg];
      y_part[ybase + (16 + hsA) * 256 + d] = (f16)acc1[dt][reg];
    }
  }
}

// ---------------- combine: y-reduce + Wv + GRU(fused Wc, 1-pass) + LN + MLP ----
// grid 256 (one slot row per block), block 1024. R9 structure minus Wc stage.
__global__ __launch_bounds__(1024) void combine_k(
    const f16* __restrict__ y_part, const float* __restrict__ sums_part,
    float* __restrict__ slots, const float* __restrict__ Wv,
    const float* __restrict__ fihT, const float* __restrict__ whhT,
    const float* __restrict__ bih, const float* __restrict__ bhh,
    const float* __restrict__ g_ml, const float* __restrict__ b_ml,
    const float* __restrict__ W1, const float* __restrict__ b1,
    const float* __restrict__ W2, const float* __restrict__ b2,
    const float* __restrict__ g_sl, const float* __restrict__ b_sl,
    const float* __restrict__ Wq, const f16* __restrict__ WkT16,
    f16* __restrict__ tq, int cq)
{
  __shared__ float ysn[4][256];
  __shared__ float uls[256], hls[256], sns[256], lns[256];
  __shared__ float hid[512];
  __shared__ float part2[4][256];
  __shared__ float part6[4][256][7];   // 6 used, 7 for bank spread
  __shared__ float part5[2][512];
  __shared__ float red[8];
  int t = threadIdx.x;
  int i = blockIdx.x;
  int b = i >> 3, k = i & 7;
  // ---- y-reduce + normalize
  {
    int j = t >> 8, d = t & 255;   // j = head
    float den = ATT_EPS, yv = 0.f;
#pragma unroll 8
    for (int ncq = 0; ncq < 32; ncq++) {
      int hsrow = (ncq * 32 + b) * 32 + j * 8 + k;
      den += sums_part[hsrow];
      yv += (float)y_part[(long)hsrow * 256 + d];
    }
    ysn[j][d] = yv / den;
    if (t < 256) hls[t] = slots[i * 256 + t];
  }
  __syncthreads();
  int col = t & 255, ks = t >> 8;
  // ---- Wv (block-diagonal per head)
  {
    int h = col >> 6;
    float acc = 0.f;
#pragma unroll 16
    for (int dd = 0; dd < 64; dd++) {
      int d = ks * 64 + dd;
      acc += ysn[h][d] * Wv[d * 256 + col];
    }
    part2[ks][col] = acc;
  }
  __syncthreads();
  if (t < 256) uls[t] = part2[0][t] + part2[1][t] + part2[2][t] + part2[3][t];
  __syncthreads();
  // ---- GRU: 6 gate dot-products in one pass; gi via fused F = Wc@wih^T
  {
    float a0 = 0.f, a1 = 0.f, a2 = 0.f, h0 = 0.f, h1 = 0.f, h2 = 0.f;
#pragma unroll 4
    for (int dd = 0; dd < 64; dd++) {
      int d = ks * 64 + dd;
      float u = uls[d], hh = hls[d];
      const float* fi = fihT + d * 768 + col;
      const float* wh = whhT + d * 768 + col;
      a0 += u * fi[0]; a1 += u * fi[256]; a2 += u * fi[512];
      h0 += hh * wh[0]; h1 += hh * wh[256]; h2 += hh * wh[512];
    }
    part6[ks][col][0] = a0; part6[ks][col][1] = a1; part6[ks][col][2] = a2;
    part6[ks][col][3] = h0; part6[ks][col][4] = h1; part6[ks][col][5] = h2;
  }
  __syncthreads();
  // ---- gates + sn + LN-reduce
  if (t < 256) {
    float gi0 = part6[0][t][0] + part6[1][t][0] + part6[2][t][0] + part6[3][t][0] + bih[t];
    float gi1 = part6[0][t][1] + part6[1][t][1] + part6[2][t][1] + part6[3][t][1] + bih[256 + t];
    float gi2 = part6[0][t][2] + part6[1][t][2] + part6[2][t][2] + part6[3][t][2] + bih[512 + t];
    float gh0 = part6[0][t][3] + part6[1][t][3] + part6[2][t][3] + part6[3][t][3] + bhh[t];
    float gh1 = part6[0][t][4] + part6[1][t][4] + part6[2][t][4] + part6[3][t][4] + bhh[256 + t];
    float gh2 = part6[0][t][5] + part6[1][t][5] + part6[2][t][5] + part6[3][t][5] + bhh[512 + t];
    float r = 1.f / (1.f + __expf(-(gi0 + gh0)));
    float z = 1.f / (1.f + __expf(-(gi1 + gh1)));
    float nc2 = tanhf(gi2 + r * gh2);
    float sn = (1.f - z) * nc2 + z * hls[t];
    sns[t] = sn;
    float a = sn, bq = sn * sn;
#pragma unroll
    for (int off = 32; off; off >>= 1) { a += __shfl_down(a, off); bq += __shfl_down(bq, off); }
    if ((t & 63) == 0) { red[t >> 6] = a; red[4 + (t >> 6)] = bq; }
  }
  __syncthreads();
  if (t < 256) {
    float S1 = red[0] + red[1] + red[2] + red[3];
    float S2 = red[4] + red[5] + red[6] + red[7];
    float mean = S1 * (1.f / 256.f);
    float var = S2 * (1.f / 256.f) - mean * mean;
    float rstd = rsqrtf(var + LN_EPS);
    lns[t] = (sns[t] - mean) * rstd * g_ml[t] + b_ml[t];
  }
  __syncthreads();
  // ---- W1
  {
    int c5 = t & 511, k5 = t >> 9;
    float acc = 0.f;
#pragma unroll 16
    for (int dd = 0; dd < 128; dd++) {
      int d = k5 * 128 + dd;
      acc += lns[d] * W1[d * 512 + c5];
    }
    part5[k5][c5] = acc;
  }
  __syncthreads();
  if (t < 512) hid[t] = fmaxf(part5[0][t] + part5[1][t] + b1[t], 0.f);
  __syncthreads();
  // ---- W2
  {
    float acc = 0.f;
#pragma unroll 16
    for (int dd = 0; dd < 128; dd++) {
      int d = ks * 128 + dd;
      acc += hid[d] * W2[d * 256 + col];
    }
    part2[ks][col] = acc;
  }
  __syncthreads();
  float outv = 0.f;
  if (t < 256) {
    outv = sns[t] + b2[t] + part2[0][t] + part2[1][t] + part2[2][t] + part2[3][t];
    slots[i * 256 + t] = outv;
  }
  if (!cq) return;   // uniform across block
  // ---- fused t for next iteration
  if (t < 256) {
    float a = outv, bq = outv * outv;
#pragma unroll
    for (int off = 32; off; off >>= 1) { a += __shfl_down(a, off); bq += __shfl_down(bq, off); }
    if ((t & 63) == 0) { red[t >> 6] = a; red[4 + (t >> 6)] = bq; }
  }
  __syncthreads();
  if (t < 256) {
    float S1 = red[0] + red[1] + red[2] + red[3];
    float S2 = red[4] + red[5] + red[6] + red[7];
    float mean = S1 * (1.f / 256.f);
    float var = S2 * (1.f / 256.f) - mean * mean;
    float rstd = rsqrtf(var + LN_EPS);
    lns[t] = (outv - mean) * rstd * g_sl[t] + b_sl[t];
  }
  __syncthreads();
  {
    float acc = 0.f;
#pragma unroll 16
    for (int dd = 0; dd < 64; dd++) {
      int d = ks * 64 + dd;
      acc += lns[d] * Wq[d * 256 + col];
    }
    part2[ks][col] = acc;
  }
  __syncthreads();
  if (t < 256) uls[t] = part2[0][t] + part2[1][t] + part2[2][t] + part2[3][t];
  __syncthreads();
  {
    int h2 = t >> 8, d2 = t & 255;
    float tt = 0.f;
#pragma unroll 8
    for (int dp = 0; dp < 64; dp++)
      tt += uls[h2 * 64 + dp] * (float)WkT16[(h2 * 64 + dp) * 256 + d2];
    tq[(b * 32 + h2 * 8 + k) * 256 + d2] = (f16)(tt * 0.125f);
  }
}

extern "C" void kernel_launch(void* const* d_in, const int* in_sizes, int n_in,
                              void* d_out, int out_size, void* d_ws, size_t ws_size,
                              hipStream_t stream)
{
  const float* inputs = (const float*)d_in[0];
  const float* noise  = (const float*)d_in[1];
  const float* mu     = (const float*)d_in[2];
  const float* lsig   = (const float*)d_in[3];
  const float* g_in   = (const float*)d_in[4];
  const float* b_in   = (const float*)d_in[5];
  const float* g_sl   = (const float*)d_in[6];
  const float* b_sl   = (const float*)d_in[7];
  const float* g_ml   = (const float*)d_in[8];
  const float* b_ml   = (const float*)d_in[9];
  const float* Wq     = (const float*)d_in[10];
  const float* Wk     = (const float*)d_in[11];
  const float* Wv     = (const float*)d_in[12];
  const float* Wc     = (const float*)d_in[13];
  const float* wih    = (const float*)d_in[14];
  const float* whh    = (const float*)d_in[15];
  const float* bih    = (const float*)d_in[16];
  const float* bhh    = (const float*)d_in[17];
  const float* W1     = (const float*)d_in[18];
  const float* b1     = (const float*)d_in[19];
  const float* W2     = (const float*)d_in[20];
  const float* b2     = (const float*)d_in[21];

  char* ws = (char*)d_ws;
  f16*   xln16  = (f16*)(ws);                      //  67,108,864
  f16*   y_part = (f16*)(ws + 67108864);           //  16,777,216
  f16*   tq     = (f16*)(ws + 83886080);           //     524,288
  float* slots  = (float*)(ws + 84410368);         //     262,144
  float* sumsp  = (float*)(ws + 84672512);         //     131,072
  f16*   WkT16  = (f16*)(ws + 84803584);           //     131,072
  float* fihT   = (float*)(ws + 84934656);         //     786,432
  float* whhT   = (float*)(ws + 85721088);         //     786,432  -> end 86,507,520

  init_slots_k<<<256, 256, 0, stream>>>(noise, mu, lsig, slots);
  prep_w_k<<<768, 256, 0, stream>>>(Wk, whh, WkT16, whhT);
  prep_f_k<<<dim3(16, 24), 256, 0, stream>>>(Wc, wih, fihT);
  ln_x_k<<<2048, 256, 0, stream>>>(inputs, g_in, b_in, xln16);
  slot_t_k<<<256, 1024, 0, stream>>>(slots, g_sl, b_sl, Wq, WkT16, tq);
  for (int it = 0; it < 3; ++it) {
    attn_fused_k<<<dim3(32, 32), 256, 0, stream>>>(xln16, tq, y_part, sumsp);
    combine_k<<<256, 1024, 0, stream>>>(y_part, sumsp, slots, Wv, fihT, whhT,
                                        bih, bhh, g_ml, b_ml, W1, b1, W2, b2,
                                        g_sl, b_sl, Wq, WkT16, tq, (it < 2) ? 1 : 0);
  }
  hipMemcpyAsync(d_out, slots, 65536 * sizeof(float), hipMemcpyDeviceToDevice, stream);
}

// Round 14
// 262.568 us; speedup vs baseline: 1.7908x; 1.0756x over previous
//
#include <hip/hip_runtime.h>
#include <hip/hip_bf16.h>
#include <stdint.h>

typedef unsigned short u16;
typedef _Float16 f16;
typedef __attribute__((ext_vector_type(4))) float f32x4;
typedef __attribute__((ext_vector_type(8))) _Float16 h16x8;
typedef __attribute__((ext_vector_type(4))) _Float16 h16x4;

#define LN_EPS 1e-5f
#define ATT_EPS 1e-8f

// ---------------- init slots: mu + exp(logsigma)*noise ----------------
__global__ __launch_bounds__(256) void init_slots_k(
    const float* __restrict__ noise, const float* __restrict__ mu,
    const float* __restrict__ lsig, float* __restrict__ slots)
{
  int i = blockIdx.x * 256 + threadIdx.x;   // 65536 total
  int d = i & 255;
  slots[i] = mu[d] + __expf(lsig[d]) * noise[i];
}

// ---------------- prep weights: WkT f16, whhT f32 ----------------
__global__ __launch_bounds__(256) void prep_w_k(
    const float* __restrict__ Wk, const float* __restrict__ whh,
    f16* __restrict__ WkT16, float* __restrict__ whhT)
{
  int i = blockIdx.x * 256 + threadIdx.x;   // grid 768 -> 196608
  if (i < 65536) {                           // WkT[c][kd] = Wk[kd][c]
    int c = i >> 8, kd = i & 255;
    WkT16[i] = (f16)Wk[kd * 256 + c];
  }
  int d = i / 768, j = i - d * 768;
  whhT[i] = whh[j * 256 + d];
}

// ---------------- prep F = Wc @ wih^T, stored as fihT[d][j] (256 x 768) ------
__global__ __launch_bounds__(256) void prep_f_k(
    const float* __restrict__ Wc, const float* __restrict__ wih,
    float* __restrict__ fihT)
{
  __shared__ float wcs[16][257];
  __shared__ float ws[32][257];
  int t = threadIdx.x;
  int d0 = blockIdx.x * 16, j0 = blockIdx.y * 32;
  for (int i = t; i < 4096; i += 256) {
    int r = i >> 8, c = i & 255;
    wcs[r][c] = Wc[(d0 + r) * 256 + c];
  }
  for (int i = t; i < 8192; i += 256) {
    int r = i >> 8, c = i & 255;
    ws[r][c] = wih[(j0 + r) * 256 + c];
  }
  __syncthreads();
  int dl = t & 15, jp = t >> 4;
  float a0 = 0.f, a1 = 0.f;
#pragma unroll 8
  for (int c = 0; c < 256; c++) {
    float wv = wcs[dl][c];
    a0 += wv * ws[jp][c];
    a1 += wv * ws[jp + 16][c];
  }
  fihT[(d0 + dl) * 768 + j0 + jp] = a0;
  fihT[(d0 + dl) * 768 + j0 + jp + 16] = a1;
}

// ---------------- pure LN pass: xln16 = LN(inputs) as f16 ----------------
__global__ __launch_bounds__(256) void ln_x_k(
    const float* __restrict__ inputs, const float* __restrict__ g_in,
    const float* __restrict__ b_in, f16* __restrict__ xln16)
{
  int t = threadIdx.x, w = t >> 6, l = t & 63;
  float4 gv = *(const float4*)(g_in + l * 4);
  float4 bv = *(const float4*)(b_in + l * 4);
  long row0 = (long)blockIdx.x * 64 + w * 16;
#pragma unroll 2
  for (int i = 0; i < 16; i++) {
    long r = row0 + i;
    float4 x = *(const float4*)(inputs + r * 256 + l * 4);
    float s1 = x.x + x.y + x.z + x.w;
    float s2 = x.x * x.x + x.y * x.y + x.z * x.z + x.w * x.w;
#pragma unroll
    for (int off = 1; off < 64; off <<= 1) {
      s1 += __shfl_xor(s1, off);
      s2 += __shfl_xor(s2, off);
    }
    float m = s1 * (1.f / 256.f);
    float var = s2 * (1.f / 256.f) - m * m;
    float rs = rsqrtf(var + LN_EPS);
    h16x4 o;
    o[0] = (f16)((x.x - m) * rs * gv.x + bv.x);
    o[1] = (f16)((x.y - m) * rs * gv.y + bv.y);
    o[2] = (f16)((x.z - m) * rs * gv.z + bv.z);
    o[3] = (f16)((x.w - m) * rs * gv.w + bv.w);
    *(h16x4*)(xln16 + r * 256 + l * 4) = o;
  }
}

// ---------------- t = (LN(slots)@Wq) projected through Wk heads, x SCALE ----
__global__ __launch_bounds__(1024) void slot_t_k(
    const float* __restrict__ slots, const float* __restrict__ g_sl,
    const float* __restrict__ b_sl, const float* __restrict__ Wq,
    const f16* __restrict__ WkT16, f16* __restrict__ tq)
{
  __shared__ float ln[256];
  __shared__ float qs[256];
  __shared__ float part[4][256];
  __shared__ float red[8];
  int t = threadIdx.x;
  int i = blockIdx.x;
  if (t < 256) {
    float x = slots[i * 256 + t];
    float a = x, bq = x * x;
#pragma unroll
    for (int off = 32; off; off >>= 1) { a += __shfl_down(a, off); bq += __shfl_down(bq, off); }
    if ((t & 63) == 0) { red[t >> 6] = a; red[4 + (t >> 6)] = bq; }
  }
  __syncthreads();
  if (t < 256) {
    float x = slots[i * 256 + t];
    float S1 = red[0] + red[1] + red[2] + red[3];
    float S2 = red[4] + red[5] + red[6] + red[7];
    float m = S1 * (1.f / 256.f);
    float var = S2 * (1.f / 256.f) - m * m;
    float rstd = rsqrtf(var + LN_EPS);
    ln[t] = (x - m) * rstd * g_sl[t] + b_sl[t];
  }
  __syncthreads();
  int col = t & 255, ks = t >> 8;
  float acc = 0.f;
#pragma unroll 16
  for (int dd = 0; dd < 64; dd++) {
    int d = ks * 64 + dd;
    acc += ln[d] * Wq[d * 256 + col];
  }
  part[ks][col] = acc;
  __syncthreads();
  if (t < 256) qs[t] = part[0][t] + part[1][t] + part[2][t] + part[3][t];
  __syncthreads();
  int h = t >> 8, d2 = t & 255;
  float tt = 0.f;
#pragma unroll 8
  for (int dp = 0; dp < 64; dp++)
    tt += qs[h * 64 + dp] * (float)WkT16[(h * 64 + dp) * 256 + d2];
  tq[((i >> 3) * 32 + h * 8 + (i & 7)) * 256 + d2] = (f16)(tt * 0.125f);
}

// ---------------- fused attn: single global read, xs + xsT dual-stage ---------
// grid (32 b, 32 nchunk of 128 n), block 256 (4 waves). 2 subtiles of 64 n.
__global__ __launch_bounds__(256, 2) void attn_fused_k(
    const f16* __restrict__ xln16, const f16* __restrict__ tq,
    f16* __restrict__ y_part, float* __restrict__ sums_part)
{
  __shared__ u16 xs[64 * 256];       // 32KB row-major: addr = nl*512 + ((sd8 ^ (nl&31))<<4)
  __shared__ u16 xsT[256 * 64];      // 32KB transposed: addr = d*128 + ((n8 ^ (d&7))<<4)
  __shared__ u16 attT[32 * 64];      // 4KB:  addr = hs*128 + ((n8 ^ (hs&7))<<4)
  __shared__ float asum_s[4][32];
  int b = blockIdx.x, nc = blockIdx.y, t = threadIdx.x;
  int nb = nc * 128;
  int w = t >> 6, l = t & 63;
  int lc = l & 15, lg = l >> 4;
  h16x8 tb0[8], tb1[8];
#pragma unroll
  for (int k0 = 0; k0 < 8; k0++) {
    tb0[k0] = *(const h16x8*)(tq + (b * 32 + lc) * 256 + k0 * 32 + lg * 8);
    tb1[k0] = *(const h16x8*)(tq + (b * 32 + lc + 16) * 256 + k0 * 32 + lg * 8);
  }
  f32x4 acc0[4], acc1[4];
#pragma unroll
  for (int dt = 0; dt < 4; dt++) { acc0[dt] = (f32x4){0,0,0,0}; acc1[dt] = (f32x4){0,0,0,0}; }
  float as0 = 0.f, as1 = 0.f;

  for (int sub = 0; sub < 2; sub++) {
    __syncthreads();   // prev PV done with xs/xsT/attT
    {
      int nl8 = t >> 5, dchunk = t & 31;
      const f16* gp = xln16 + ((long)(b * 4096 + nb + sub * 64 + nl8 * 8)) * 256 + dchunk * 8;
      h16x8 v0 = *(const h16x8*)(gp);
      h16x8 v1 = *(const h16x8*)(gp + 256);
      h16x8 v2 = *(const h16x8*)(gp + 512);
      h16x8 v3 = *(const h16x8*)(gp + 768);
      h16x8 v4 = *(const h16x8*)(gp + 1024);
      h16x8 v5 = *(const h16x8*)(gp + 1280);
      h16x8 v6 = *(const h16x8*)(gp + 1536);
      h16x8 v7 = *(const h16x8*)(gp + 1792);
      // xs: row-major (dots A-frags)
      {
        int r0 = nl8 * 8;
        *(h16x8*)((char*)xs + (r0 + 0) * 512 + ((dchunk ^ ((r0 + 0) & 31)) << 4)) = v0;
        *(h16x8*)((char*)xs + (r0 + 1) * 512 + ((dchunk ^ ((r0 + 1) & 31)) << 4)) = v1;
        *(h16x8*)((char*)xs + (r0 + 2) * 512 + ((dchunk ^ ((r0 + 2) & 31)) << 4)) = v2;
        *(h16x8*)((char*)xs + (r0 + 3) * 512 + ((dchunk ^ ((r0 + 3) & 31)) << 4)) = v3;
        *(h16x8*)((char*)xs + (r0 + 4) * 512 + ((dchunk ^ ((r0 + 4) & 31)) << 4)) = v4;
        *(h16x8*)((char*)xs + (r0 + 5) * 512 + ((dchunk ^ ((r0 + 5) & 31)) << 4)) = v5;
        *(h16x8*)((char*)xs + (r0 + 6) * 512 + ((dchunk ^ ((r0 + 6) & 31)) << 4)) = v6;
        *(h16x8*)((char*)xs + (r0 + 7) * 512 + ((dchunk ^ ((r0 + 7) & 31)) << 4)) = v7;
      }
      // xsT: in-register transpose (PV B-frags)
#pragma unroll
      for (int j = 0; j < 8; j++) {
        h16x8 o;
        o[0] = v0[j]; o[1] = v1[j]; o[2] = v2[j]; o[3] = v3[j];
        o[4] = v4[j]; o[5] = v5[j]; o[6] = v6[j]; o[7] = v7[j];
        int d = dchunk * 8 + j;
        *(h16x8*)((char*)xsT + d * 128 + ((nl8 ^ j) << 4)) = o;
      }
    }
    __syncthreads();   // xs + xsT ready
    // dots: A-frags from xs (LDS), B = hoisted t
    f32x4 D0 = {0,0,0,0}, D1 = {0,0,0,0};
    {
      int row = w * 16 + lc, sw = row & 31;
#pragma unroll
      for (int k0 = 0; k0 < 8; k0++) {
        int sd8 = k0 * 4 + lg;
        h16x8 af = *(const h16x8*)((char*)xs + row * 512 + ((sd8 ^ sw) << 4));
        D0 = __builtin_amdgcn_mfma_f32_16x16x32_f16(af, tb0[k0], D0, 0, 0, 0);
        D1 = __builtin_amdgcn_mfma_f32_16x16x32_f16(af, tb1[k0], D1, 0, 0, 0);
      }
    }
    h16x4 pk0, pk1;
#pragma unroll
    for (int r = 0; r < 4; r++) {
      float d0 = D0[r], d1 = D1[r];
      float m0 = d0, m1 = d1;
      m0 = fmaxf(m0, __shfl_xor(m0, 1)); m0 = fmaxf(m0, __shfl_xor(m0, 2)); m0 = fmaxf(m0, __shfl_xor(m0, 4));
      m1 = fmaxf(m1, __shfl_xor(m1, 1)); m1 = fmaxf(m1, __shfl_xor(m1, 2)); m1 = fmaxf(m1, __shfl_xor(m1, 4));
      float e0 = __expf(d0 - m0), e1 = __expf(d1 - m1);
      float s0 = e0, s1 = e1;
      s0 += __shfl_xor(s0, 1); s0 += __shfl_xor(s0, 2); s0 += __shfl_xor(s0, 4);
      s1 += __shfl_xor(s1, 1); s1 += __shfl_xor(s1, 2); s1 += __shfl_xor(s1, 4);
      f16 a0h = (f16)(e0 / s0), a1h = (f16)(e1 / s1);
      as0 += (float)a0h; as1 += (float)a1h;
      pk0[r] = a0h; pk1[r] = a1h;
    }
    {
      int slot = w * 2 + (lg >> 1);
      int boff = (lg & 1) * 8;
      *(h16x4*)((char*)attT + lc * 128 + ((slot ^ (lc & 7)) << 4) + boff) = pk0;
      *(h16x4*)((char*)attT + (lc + 16) * 128 + ((slot ^ (lc & 7)) << 4) + boff) = pk1;
    }
    __syncthreads();   // attT ready
    // PV via MFMA: A = attT, B = xsT
    h16x8 A00, A01, A10, A11;
    {
      int hs0 = lc, hs1 = 16 + lc, sw = lc & 7;
      A00 = *(const h16x8*)((char*)attT + hs0 * 128 + ((lg ^ sw) << 4));
      A01 = *(const h16x8*)((char*)attT + hs0 * 128 + (((4 + lg) ^ sw) << 4));
      A10 = *(const h16x8*)((char*)attT + hs1 * 128 + ((lg ^ sw) << 4));
      A11 = *(const h16x8*)((char*)attT + hs1 * 128 + (((4 + lg) ^ sw) << 4));
    }
#pragma unroll
    for (int dt = 0; dt < 4; dt++) {
      int d = w * 64 + dt * 16 + lc;
      h16x8 B0 = *(const h16x8*)((char*)xsT + d * 128 + ((lg ^ (d & 7)) << 4));
      h16x8 B1 = *(const h16x8*)((char*)xsT + d * 128 + (((4 + lg) ^ (d & 7)) << 4));
      acc0[dt] = __builtin_amdgcn_mfma_f32_16x16x32_f16(A00, B0, acc0[dt], 0, 0, 0);
      acc0[dt] = __builtin_amdgcn_mfma_f32_16x16x32_f16(A01, B1, acc0[dt], 0, 0, 0);
      acc1[dt] = __builtin_amdgcn_mfma_f32_16x16x32_f16(A10, B0, acc1[dt], 0, 0, 0);
      acc1[dt] = __builtin_amdgcn_mfma_f32_16x16x32_f16(A11, B1, acc1[dt], 0, 0, 0);
    }
  }
  as0 += __shfl_xor(as0, 16); as0 += __shfl_xor(as0, 32);
  as1 += __shfl_xor(as1, 16); as1 += __shfl_xor(as1, 32);
  if (l < 16) { asum_s[w][l] = as0; asum_s[w][l + 16] = as1; }
  __syncthreads();
  if (t < 32)
    sums_part[(nc * 32 + b) * 32 + t] =
        asum_s[0][t] + asum_s[1][t] + asum_s[2][t] + asum_s[3][t];
  long ybase = ((long)(nc * 32 + b) * 32) * 256;
#pragma unroll
  for (int reg = 0; reg < 4; reg++) {
    int hsA = lg * 4 + reg;
#pragma unroll
    for (int dt = 0; dt < 4; dt++) {
      int d = w * 64 + dt * 16 + lc;
      y_part[ybase + hsA * 256 + d] = (f16)acc0[dt][reg];
      y_part[ybase + (16 + hsA) * 256 + d] = (f16)acc1[dt][reg];
    }
  }
}

// ---------------- combine: float4 col-quad matvecs; GRU unchanged -------------
// grid 256 (one slot row per block), block 1024.
__global__ __launch_bounds__(1024) void combine_k(
    const f16* __restrict__ y_part, const float* __restrict__ sums_part,
    float* __restrict__ slots, const float* __restrict__ Wv,
    const float* __restrict__ fihT, const float* __restrict__ whhT,
    const float* __restrict__ bih, const float* __restrict__ bhh,
    const float* __restrict__ g_ml, const float* __restrict__ b_ml,
    const float* __restrict__ W1, const float* __restrict__ b1,
    const float* __restrict__ W2, const float* __restrict__ b2,
    const float* __restrict__ g_sl, const float* __restrict__ b_sl,
    const float* __restrict__ Wq, const f16* __restrict__ WkT16,
    f16* __restrict__ tq, int cq)
{
  __shared__ float ysn[4][256];
  __shared__ float uls[256], hls[256], sns[256], lns[256];
  __shared__ float hid[512];
  __shared__ f32x4 part16[16][64];     // 16KB, read as float[16][256]
  __shared__ f32x4 part5q[8][128];     // 16KB, read as float[8][512]
  __shared__ float part6[4][256][7];   // 28KB
  __shared__ float red[8];
  int t = threadIdx.x;
  int i = blockIdx.x;
  int b = i >> 3, k = i & 7;
  // ---- y-reduce + normalize
  {
    int j = t >> 8, d = t & 255;   // j = head
    float den = ATT_EPS, yv = 0.f;
#pragma unroll 8
    for (int ncq = 0; ncq < 32; ncq++) {
      int hsrow = (ncq * 32 + b) * 32 + j * 8 + k;
      den += sums_part[hsrow];
      yv += (float)y_part[(long)hsrow * 256 + d];
    }
    ysn[j][d] = yv / den;
    if (t < 256) hls[t] = slots[i * 256 + t];
  }
  __syncthreads();
  int col = t & 255, ks = t >> 8;          // legacy decomposition (GRU, WkT)
  int qc = t & 63, ks16 = t >> 6;          // col-quad decomposition
  int col0 = qc * 4;
  const float* p16 = (const float*)part16;
  const float* p5 = (const float*)part5q;
  // ---- Wv (block-diagonal per head), float4 col-quad
  {
    int h = col0 >> 6;
    f32x4 acc = {0.f, 0.f, 0.f, 0.f};
#pragma unroll
    for (int dd = 0; dd < 16; dd++) {
      int d = ks16 * 16 + dd;
      float u = ysn[h][d];
      float4 wv = *(const float4*)(Wv + d * 256 + col0);
      acc[0] += u * wv.x; acc[1] += u * wv.y; acc[2] += u * wv.z; acc[3] += u * wv.w;
    }
    part16[ks16][qc] = acc;
  }
  __syncthreads();
  if (t < 256) {
    float s = 0.f;
#pragma unroll
    for (int q = 0; q < 16; q++) s += p16[q * 256 + t];
    uls[t] = s;
  }
  __syncthreads();
  // ---- GRU: 6 gate dot-products in one pass (unchanged structure)
  {
    float a0 = 0.f, a1 = 0.f, a2 = 0.f, h0 = 0.f, h1 = 0.f, h2 = 0.f;
#pragma unroll 4
    for (int dd = 0; dd < 64; dd++) {
      int d = ks * 64 + dd;
      float u = uls[d], hh = hls[d];
      const float* fi = fihT + d * 768 + col;
      const float* wh = whhT + d * 768 + col;
      a0 += u * fi[0]; a1 += u * fi[256]; a2 += u * fi[512];
      h0 += hh * wh[0]; h1 += hh * wh[256]; h2 += hh * wh[512];
    }
    part6[ks][col][0] = a0; part6[ks][col][1] = a1; part6[ks][col][2] = a2;
    part6[ks][col][3] = h0; part6[ks][col][4] = h1; part6[ks][col][5] = h2;
  }
  __syncthreads();
  // ---- gates + sn + LN-reduce
  if (t < 256) {
    float gi0 = part6[0][t][0] + part6[1][t][0] + part6[2][t][0] + part6[3][t][0] + bih[t];
    float gi1 = part6[0][t][1] + part6[1][t][1] + part6[2][t][1] + part6[3][t][1] + bih[256 + t];
    float gi2 = part6[0][t][2] + part6[1][t][2] + part6[2][t][2] + part6[3][t][2] + bih[512 + t];
    float gh0 = part6[0][t][3] + part6[1][t][3] + part6[2][t][3] + part6[3][t][3] + bhh[t];
    float gh1 = part6[0][t][4] + part6[1][t][4] + part6[2][t][4] + part6[3][t][4] + bhh[256 + t];
    float gh2 = part6[0][t][5] + part6[1][t][5] + part6[2][t][5] + part6[3][t][5] + bhh[512 + t];
    float r = 1.f / (1.f + __expf(-(gi0 + gh0)));
    float z = 1.f / (1.f + __expf(-(gi1 + gh1)));
    float nc2 = tanhf(gi2 + r * gh2);
    float sn = (1.f - z) * nc2 + z * hls[t];
    sns[t] = sn;
    float a = sn, bq = sn * sn;
#pragma unroll
    for (int off = 32; off; off >>= 1) { a += __shfl_down(a, off); bq += __shfl_down(bq, off); }
    if ((t & 63) == 0) { red[t >> 6] = a; red[4 + (t >> 6)] = bq; }
  }
  __syncthreads();
  if (t < 256) {
    float S1 = red[0] + red[1] + red[2] + red[3];
    float S2 = red[4] + red[5] + red[6] + red[7];
    float mean = S1 * (1.f / 256.f);
    float var = S2 * (1.f / 256.f) - mean * mean;
    float rstd = rsqrtf(var + LN_EPS);
    lns[t] = (sns[t] - mean) * rstd * g_ml[t] + b_ml[t];
  }
  __syncthreads();
  // ---- W1: float4 col-quad (512 cols: 128 quads x 8 slices of 32 d)
  {
    int qc5 = t & 127, ks8 = t >> 7;
    int c0 = qc5 * 4;
    f32x4 acc = {0.f, 0.f, 0.f, 0.f};
#pragma unroll
    for (int dd = 0; dd < 32; dd++) {
      int d = ks8 * 32 + dd;
      float u = lns[d];
      float4 wv = *(const float4*)(W1 + d * 512 + c0);
      acc[0] += u * wv.x; acc[1] += u * wv.y; acc[2] += u * wv.z; acc[3] += u * wv.w;
    }
    part5q[ks8][qc5] = acc;
  }
  __syncthreads();
  if (t < 512) {
    float s = 0.f;
#pragma unroll
    for (int q = 0; q < 8; q++) s += p5[q * 512 + t];
    hid[t] = fmaxf(s + b1[t], 0.f);
  }
  __syncthreads();
  // ---- W2: float4 col-quad (contraction 512: 16 slices of 32)
  {
    f32x4 acc = {0.f, 0.f, 0.f, 0.f};
#pragma unroll
    for (int dd = 0; dd < 32; dd++) {
      int d = ks16 * 32 + dd;
      float u = hid[d];
      float4 wv = *(const float4*)(W2 + d * 256 + col0);
      acc[0] += u * wv.x; acc[1] += u * wv.y; acc[2] += u * wv.z; acc[3] += u * wv.w;
    }
    part16[ks16][qc] = acc;
  }
  __syncthreads();
  float outv = 0.f;
  if (t < 256) {
    float s = 0.f;
#pragma unroll
    for (int q = 0; q < 16; q++) s += p16[q * 256 + t];
    outv = sns[t] + b2[t] + s;
    slots[i * 256 + t] = outv;
  }
  if (!cq) return;   // uniform across block
  // ---- fused t for next iteration
  if (t < 256) {
    float a = outv, bq = outv * outv;
#pragma unroll
    for (int off = 32; off; off >>= 1) { a += __shfl_down(a, off); bq += __shfl_down(bq, off); }
    if ((t & 63) == 0) { red[t >> 6] = a; red[4 + (t >> 6)] = bq; }
  }
  __syncthreads();
  if (t < 256) {
    float S1 = red[0] + red[1] + red[2] + red[3];
    float S2 = red[4] + red[5] + red[6] + red[7];
    float mean = S1 * (1.f / 256.f);
    float var = S2 * (1.f / 256.f) - mean * mean;
    float rstd = rsqrtf(var + LN_EPS);
    lns[t] = (outv - mean) * rstd * g_sl[t] + b_sl[t];
  }
  __syncthreads();
  // ---- Wq: float4 col-quad
  {
    f32x4 acc = {0.f, 0.f, 0.f, 0.f};
#pragma unroll
    for (int dd = 0; dd < 16; dd++) {
      int d = ks16 * 16 + dd;
      float u = lns[d];
      float4 wv = *(const float4*)(Wq + d * 256 + col0);
      acc[0] += u * wv.x; acc[1] += u * wv.y; acc[2] += u * wv.z; acc[3] += u * wv.w;
    }
    part16[ks16][qc] = acc;
  }
  __syncthreads();
  if (t < 256) {
    float s = 0.f;
#pragma unroll
    for (int q = 0; q < 16; q++) s += p16[q * 256 + t];
    uls[t] = s;
  }
  __syncthreads();
  {
    int h2 = t >> 8, d2 = t & 255;
    float tt = 0.f;
#pragma unroll 8
    for (int dp = 0; dp < 64; dp++)
      tt += uls[h2 * 64 + dp] * (float)WkT16[(h2 * 64 + dp) * 256 + d2];
    tq[(b * 32 + h2 * 8 + k) * 256 + d2] = (f16)(tt * 0.125f);
  }
}

extern "C" void kernel_launch(void* const* d_in, const int* in_sizes, int n_in,
                              void* d_out, int out_size, void* d_ws, size_t ws_size,
                              hipStream_t stream)
{
  const float* inputs = (const float*)d_in[0];
  const float* noise  = (const float*)d_in[1];
  const float* mu     = (const float*)d_in[2];
  const float* lsig   = (const float*)d_in[3];
  const float* g_in   = (const float*)d_in[4];
  const float* b_in   = (const float*)d_in[5];
  const float* g_sl   = (const float*)d_in[6];
  const float* b_sl   = (const float*)d_in[7];
  const float* g_ml   = (const float*)d_in[8];
  const float* b_ml   = (const float*)d_in[9];
  const float* Wq     = (const float*)d_in[10];
  const float* Wk     = (const float*)d_in[11];
  const float* Wv     = (const float*)d_in[12];
  const float* Wc     = (const float*)d_in[13];
  const float* wih    = (const float*)d_in[14];
  const float* whh    = (const float*)d_in[15];
  const float* bih    = (const float*)d_in[16];
  const float* bhh    = (const float*)d_in[17];
  const float* W1     = (const float*)d_in[18];
  const float* b1     = (const float*)d_in[19];
  const float* W2     = (const float*)d_in[20];
  const float* b2     = (const float*)d_in[21];

  char* ws = (char*)d_ws;
  f16*   xln16  = (f16*)(ws);                      //  67,108,864
  f16*   y_part = (f16*)(ws + 67108864);           //  16,777,216
  f16*   tq     = (f16*)(ws + 83886080);           //     524,288
  float* slots  = (float*)(ws + 84410368);         //     262,144
  float* sumsp  = (float*)(ws + 84672512);         //     131,072
  f16*   WkT16  = (f16*)(ws + 84803584);           //     131,072
  float* fihT   = (float*)(ws + 84934656);         //     786,432
  float* whhT   = (float*)(ws + 85721088);         //     786,432  -> end 86,507,520

  init_slots_k<<<256, 256, 0, stream>>>(noise, mu, lsig, slots);
  prep_w_k<<<768, 256, 0, stream>>>(Wk, whh, WkT16, whhT);
  prep_f_k<<<dim3(16, 24), 256, 0, stream>>>(Wc, wih, fihT);
  ln_x_k<<<2048, 256, 0, stream>>>(inputs, g_in, b_in, xln16);
  slot_t_k<<<256, 1024, 0, stream>>>(slots, g_sl, b_sl, Wq, WkT16, tq);
  for (int it = 0; it < 3; ++it) {
    attn_fused_k<<<dim3(32, 32), 256, 0, stream>>>(xln16, tq, y_part, sumsp);
    combine_k<<<256, 1024, 0, stream>>>(y_part, sumsp, slots, Wv, fihT, whhT,
                                        bih, bhh, g_ml, b_ml, W1, b1, W2, b2,
                                        g_sl, b_sl, Wq, WkT16, tq, (it < 2) ? 1 : 0);
  }
  hipMemcpyAsync(d_out, slots, 65536 * sizeof(float), hipMemcpyDeviceToDevice, stream);
}